// Round 5
// baseline (932.722 us; speedup 1.0000x reference)
//
#include <hip/hip_runtime.h>

#define HF 128
#define OUTF 16
#define NG 64
#define NB 1024            // CSR build buckets; PB = ceil(n/NB) must be <= 256
#define BN_EPS 1e-5f

typedef unsigned short ushortT;
typedef unsigned int uintT;

__device__ __forceinline__ float bf2f(uintT u) {
    union { uintT i; float f; } c; c.i = u << 16; return c.f;
}
__device__ __forceinline__ float bf2f_hi(uintT u) {
    union { uintT i; float f; } c; c.i = u & 0xffff0000u; return c.f;
}
__device__ __forceinline__ uintT f2bf(float f) {
    union { float f; uintT i; } c; c.f = f;
    uintT u = c.i;
    return (u + 0x7fffu + ((u >> 16) & 1u)) >> 16;
}
__device__ __forceinline__ uintT pack2(float a, float b) {
    return f2bf(a) | (f2bf(b) << 16);
}

// ---------------- degree (int) / normalization ----------------

__global__ void degi_kernel(const int* __restrict__ dst, int* __restrict__ degi, int E) {
    int e = blockIdx.x * blockDim.x + threadIdx.x;
    if (e < E) atomicAdd(&degi[dst[e]], 1);
}

__global__ void dis_xp_kernel(const int* __restrict__ degi, const float* __restrict__ x,
                              float* __restrict__ dis, float* __restrict__ xp, int n) {
    int i = blockIdx.x * blockDim.x + threadIdx.x;
    if (i < n) {
        float d = rsqrtf((float)degi[i] + 1.0f);   // +1 = self loop
        dis[i] = d;
        xp[i] = d * x[i];
    }
}

// ---------------- prefix sum (rowptr over deg; no self-loop entries) ----------------

__global__ __launch_bounds__(256) void scan_partial(const int* __restrict__ degi,
                                                    int* __restrict__ blocksums, int n) {
    __shared__ int sdata[256];
    int b = blockIdx.x, t = threadIdx.x;
    int s = 0;
    for (int k = t; k < 1024; k += 256) {
        int i = b * 1024 + k;
        if (i < n) s += degi[i];
    }
    sdata[t] = s; __syncthreads();
    for (int o = 128; o > 0; o >>= 1) {
        if (t < o) sdata[t] += sdata[t + o];
        __syncthreads();
    }
    if (t == 0) blocksums[b] = sdata[0];
}

__global__ void scan_sums(int* __restrict__ blocksums, int nb) {
    if (threadIdx.x == 0) {
        int run = 0;
        for (int i = 0; i < nb; ++i) { int v = blocksums[i]; blocksums[i] = run; run += v; }
    }
}

__global__ __launch_bounds__(256) void scan_final(const int* __restrict__ degi,
                                                  const int* __restrict__ blocksums,
                                                  int* __restrict__ rowptr, int n) {
    int b = blockIdx.x, t = threadIdx.x;
    int base = b * 1024 + t * 4;
    int v[4]; int s = 0;
    for (int k = 0; k < 4; ++k) {
        int i = base + k;
        v[k] = (i < n) ? degi[i] : 0;
        s += v[k];
    }
    __shared__ int ts[256];
    ts[t] = s; __syncthreads();
    for (int o = 1; o < 256; o <<= 1) {
        int val = (t >= o) ? ts[t - o] : 0;
        __syncthreads();
        ts[t] += val;
        __syncthreads();
    }
    int off = blocksums[b] + ((t > 0) ? ts[t - 1] : 0);
    for (int k = 0; k < 4; ++k) {
        int i = base + k;
        if (i < n) {
            rowptr[i] = off;
            off += v[k];
            if (i == n - 1) rowptr[n] = off;
        }
    }
}

// ---------------- bucketed CSR build ----------------

__global__ void binit_kernel(const int* __restrict__ rowptr, int* __restrict__ bcur,
                             int n, int PB) {
    int b = blockIdx.x * blockDim.x + threadIdx.x;
    if (b < NB) bcur[b] = rowptr[min(b * PB, n)];
}

// tmp[pos] = (local_dst << 18) | src   (src < 2^18, local_dst < 2^14)
__global__ void bucket_scatter_kernel(const int* __restrict__ src, const int* __restrict__ dst,
                                      int* __restrict__ bcur, uintT* __restrict__ tmp,
                                      int E, int PB) {
    int e = blockIdx.x * blockDim.x + threadIdx.x;
    if (e < E) {
        int s = src[e], d = dst[e];
        int b = d / PB;
        int pos = atomicAdd(&bcur[b], 1);
        tmp[pos] = ((uintT)(d - b * PB) << 18) | (uintT)s;
    }
}

__global__ __launch_bounds__(256) void bucket_reorder_kernel(const uintT* __restrict__ tmp,
                                                             const int* __restrict__ rowptr,
                                                             int* __restrict__ csr_src,
                                                             int n, int PB) {
    __shared__ int lcur[256];          // PB <= 256
    __shared__ int stage[4096];
    int b = blockIdx.x;
    int n0 = b * PB;
    if (n0 >= n) return;
    int n1 = min(n0 + PB, n);
    int t = threadIdx.x;
    int start = rowptr[n0], end = rowptr[n1];
    int cnt = end - start;
    for (int i = t; i < n1 - n0; i += 256) lcur[i] = rowptr[n0 + i] - start;
    __syncthreads();
    if (cnt <= 4096) {
        for (int i = t; i < cnt; i += 256) {
            uintT p = tmp[start + i];
            int ldst = p >> 18;
            int pos = atomicAdd(&lcur[ldst], 1);
            stage[pos] = (int)(p & 0x3ffffu);
        }
        __syncthreads();
        for (int i = t; i < cnt; i += 256) csr_src[start + i] = stage[i];
    } else {
        for (int i = t; i < cnt; i += 256) {
            uintT p = tmp[start + i];
            int ldst = p >> 18;
            int pos = atomicAdd(&lcur[ldst], 1);
            csr_src[start + pos] = (int)(p & 0x3ffffu);
        }
    }
}

// ---------------- layer 0: scalar gather (xp = dis*x) ----------------

__global__ void gather1_kernel(const float* __restrict__ xp, const int* __restrict__ rowptr,
                               const int* __restrict__ csr_src, const float* __restrict__ dis,
                               float* __restrict__ aggx, int n) {
    int i = blockIdx.x * blockDim.x + threadIdx.x;
    if (i >= n) return;
    float acc = xp[i];                // self loop
    int e = rowptr[i + 1];
    for (int j = rowptr[i]; j < e; ++j) acc += xp[csr_src[j]];
    aggx[i] = acc * dis[i];
}

__global__ void stats1_kernel(const float* __restrict__ aggx, float* __restrict__ stats1, int n) {
    float s = 0.f, ss = 0.f;
    for (int i = blockIdx.x * blockDim.x + threadIdx.x; i < n; i += gridDim.x * blockDim.x) {
        float v = aggx[i]; s += v; ss += v * v;
    }
    for (int o = 32; o > 0; o >>= 1) { s += __shfl_down(s, o); ss += __shfl_down(ss, o); }
    if ((threadIdx.x & 63) == 0) { atomicAdd(&stats1[0], s); atomicAdd(&stats1[1], ss); }
}

__global__ void coef0_kernel(const float* __restrict__ stats1, const float* __restrict__ W0,
                             const float* __restrict__ g, const float* __restrict__ beta,
                             float* __restrict__ coef, float invn) {
    int j = threadIdx.x;
    if (j < HF) {
        float m = stats1[0] * invn;
        float var = stats1[1] * invn - m * m;
        float w = W0[j];
        float sc = g[j] * w * rsqrtf(var * w * w + BN_EPS);
        coef[j] = sc;
        coef[HF + j] = beta[j] - m * sc;
    }
}

__global__ void h0_kernel(const float* __restrict__ aggx, const float* __restrict__ coef,
                          ushortT* __restrict__ h0, int n) {
    int idx = blockIdx.x * blockDim.x + threadIdx.x;
    if (idx >= n * (HF / 4)) return;
    int i = idx >> 5, jc = idx & 31;
    float a = aggx[i];
    float4 sc = reinterpret_cast<const float4*>(coef)[jc];
    float4 sh = reinterpret_cast<const float4*>(coef + HF)[jc];
    float o0 = fmaxf(a * sc.x + sh.x, 0.f);
    float o1 = fmaxf(a * sc.y + sh.y, 0.f);
    float o2 = fmaxf(a * sc.z + sh.z, 0.f);
    float o3 = fmaxf(a * sc.w + sh.w, 0.f);
    uint2 o; o.x = pack2(o0, o1); o.y = pack2(o2, o3);
    reinterpret_cast<uint2*>(h0)[idx] = o;
}

// ---------------- GEMM: C[n,128] = dis[row] * (act(A)[n,128] @ W[128,128]) ----------------

__global__ __launch_bounds__(256) void gemm128_kernel(const ushortT* __restrict__ A,
                                                      const float* __restrict__ W,
                                                      const float* __restrict__ coef,
                                                      const float* __restrict__ dis,
                                                      ushortT* __restrict__ C, int n,
                                                      int applyCoef) {
    __shared__ float Ws[128 * 128];
    __shared__ float As[16][128];
    int t = threadIdx.x;
    for (int i = t; i < 128 * 128; i += 256) Ws[i] = W[i];
    int rowBase = blockIdx.x * 16;
    for (int i = t; i < 16 * 32; i += 256) {
        int rr = i >> 5, g = i & 31;
        int r = rowBase + rr;
        uint2 v = make_uint2(0u, 0u);
        if (r < n) v = *reinterpret_cast<const uint2*>(A + (size_t)r * HF + g * 4);
        float f0 = bf2f(v.x & 0xffff), f1 = bf2f_hi(v.x);
        float f2 = bf2f(v.y & 0xffff), f3 = bf2f_hi(v.y);
        if (applyCoef) {
            int c = g * 4;
            f0 = fmaxf(f0 * coef[c + 0] + coef[HF + c + 0], 0.f);
            f1 = fmaxf(f1 * coef[c + 1] + coef[HF + c + 1], 0.f);
            f2 = fmaxf(f2 * coef[c + 2] + coef[HF + c + 2], 0.f);
            f3 = fmaxf(f3 * coef[c + 3] + coef[HF + c + 3], 0.f);
        }
        As[rr][g * 4 + 0] = f0;
        As[rr][g * 4 + 1] = f1;
        As[rr][g * 4 + 2] = f2;
        As[rr][g * 4 + 3] = f3;
    }
    __syncthreads();
    int jc = t & 31;
    int rs = t >> 5;
    float4 acc0 = {0, 0, 0, 0}, acc1 = {0, 0, 0, 0};
    for (int k = 0; k < 128; ++k) {
        float4 w = reinterpret_cast<const float4*>(Ws + k * 128)[jc];
        float a0 = As[rs][k], a1 = As[rs + 8][k];
        acc0.x += a0 * w.x; acc0.y += a0 * w.y; acc0.z += a0 * w.z; acc0.w += a0 * w.w;
        acc1.x += a1 * w.x; acc1.y += a1 * w.y; acc1.z += a1 * w.z; acc1.w += a1 * w.w;
    }
    int r0 = rowBase + rs, r1 = r0 + 8;
    if (r0 < n) {
        float d0 = dis[r0];
        uint2 o; o.x = pack2(acc0.x * d0, acc0.y * d0); o.y = pack2(acc0.z * d0, acc0.w * d0);
        *reinterpret_cast<uint2*>(C + (size_t)r0 * HF + jc * 4) = o;
    }
    if (r1 < n) {
        float d1 = dis[r1];
        uint2 o; o.x = pack2(acc1.x * d1, acc1.y * d1); o.y = pack2(acc1.z * d1, acc1.w * d1);
        *reinterpret_cast<uint2*>(C + (size_t)r1 * HF + jc * 4) = o;
    }
}

// ---------------- CSR gather: agg[d] = dis[d]*(sum src rows + own row) ----------------

__global__ __launch_bounds__(256) void gather128_kernel(const ushortT* __restrict__ h2,
                                                        const int* __restrict__ rowptr,
                                                        const int* __restrict__ csr_src,
                                                        const float* __restrict__ dis,
                                                        ushortT* __restrict__ agg, int n) {
    int node = (blockIdx.x * 256 + threadIdx.x) >> 6;
    int lane = threadIdx.x & 63;
    if (node >= n) return;
    int beg = rowptr[node], end = rowptr[node + 1];
    uintT vs = *reinterpret_cast<const uintT*>(h2 + (size_t)node * HF + lane * 2);
    float a0 = bf2f(vs & 0xffff), a1 = bf2f_hi(vs);
    for (int base = beg; base < end; base += 64) {
        int idx = base + lane;
        int sj = (idx < end) ? csr_src[idx] : 0;
        int cnt = min(64, end - base);
        int j = 0;
        for (; j + 4 <= cnt; j += 4) {
            int s0 = __shfl(sj, j);
            int s1 = __shfl(sj, j + 1);
            int s2 = __shfl(sj, j + 2);
            int s3 = __shfl(sj, j + 3);
            uintT v0 = *reinterpret_cast<const uintT*>(h2 + (size_t)s0 * HF + lane * 2);
            uintT v1 = *reinterpret_cast<const uintT*>(h2 + (size_t)s1 * HF + lane * 2);
            uintT v2 = *reinterpret_cast<const uintT*>(h2 + (size_t)s2 * HF + lane * 2);
            uintT v3 = *reinterpret_cast<const uintT*>(h2 + (size_t)s3 * HF + lane * 2);
            a0 += bf2f(v0 & 0xffff); a1 += bf2f_hi(v0);
            a0 += bf2f(v1 & 0xffff); a1 += bf2f_hi(v1);
            a0 += bf2f(v2 & 0xffff); a1 += bf2f_hi(v2);
            a0 += bf2f(v3 & 0xffff); a1 += bf2f_hi(v3);
        }
        for (; j < cnt; ++j) {
            int s = __shfl(sj, j);
            uintT v = *reinterpret_cast<const uintT*>(h2 + (size_t)s * HF + lane * 2);
            a0 += bf2f(v & 0xffff); a1 += bf2f_hi(v);
        }
    }
    float dd = dis[node];
    *reinterpret_cast<uintT*>(agg + (size_t)node * HF + lane * 2) = pack2(a0 * dd, a1 * dd);
}

// ---------------- BN stats / coef ----------------

__global__ __launch_bounds__(256) void bn_stats_kernel(const ushortT* __restrict__ a,
                                                       float* __restrict__ stats, int n) {
    int lane = threadIdx.x & 63;
    int sub = threadIdx.x >> 6;
    float s0 = 0.f, s1 = 0.f, ss0 = 0.f, ss1 = 0.f;
    for (int r = blockIdx.x * 4 + sub; r < n; r += gridDim.x * 4) {
        uintT v = *reinterpret_cast<const uintT*>(a + (size_t)r * HF + lane * 2);
        float x0 = bf2f(v & 0xffff), x1 = bf2f_hi(v);
        s0 += x0; ss0 += x0 * x0;
        s1 += x1; ss1 += x1 * x1;
    }
    __shared__ float red[4][4][64];
    red[0][sub][lane] = s0; red[1][sub][lane] = s1;
    red[2][sub][lane] = ss0; red[3][sub][lane] = ss1;
    __syncthreads();
    if (sub == 0) {
        float S0 = red[0][0][lane] + red[0][1][lane] + red[0][2][lane] + red[0][3][lane];
        float S1 = red[1][0][lane] + red[1][1][lane] + red[1][2][lane] + red[1][3][lane];
        float T0 = red[2][0][lane] + red[2][1][lane] + red[2][2][lane] + red[2][3][lane];
        float T1 = red[3][0][lane] + red[3][1][lane] + red[3][2][lane] + red[3][3][lane];
        atomicAdd(&stats[lane * 2], S0);
        atomicAdd(&stats[lane * 2 + 1], S1);
        atomicAdd(&stats[HF + lane * 2], T0);
        atomicAdd(&stats[HF + lane * 2 + 1], T1);
    }
}

__global__ void bn_coef_kernel(const float* __restrict__ stats, const float* __restrict__ g,
                               const float* __restrict__ beta, float* __restrict__ coef,
                               float invn) {
    int j = threadIdx.x;
    if (j < HF) {
        float m = stats[j] * invn;
        float v = stats[HF + j] * invn - m * m;
        float sc = g[j] * rsqrtf(v + BN_EPS);
        coef[j] = sc;
        coef[HF + j] = beta[j] - m * sc;
    }
}

// ---------------- pooling (fused BN+ReLU of layer 2) ----------------

__global__ void starts_kernel(const int* __restrict__ batch, int* __restrict__ starts, int n) {
    int g = threadIdx.x;
    if (g > NG) return;
    int lo = 0, hi = n;
    while (lo < hi) {
        int mid = (lo + hi) >> 1;
        if (batch[mid] < g) lo = mid + 1; else hi = mid;
    }
    starts[g] = lo;
}

__global__ void pool_kernel(const ushortT* __restrict__ h, const float* __restrict__ coef,
                            const int* __restrict__ starts, float* __restrict__ pooled) {
    int g = blockIdx.x >> 4;
    int p = blockIdx.x & 15;
    int lane = threadIdx.x;
    float sc0 = coef[lane * 2],     sc1 = coef[lane * 2 + 1];
    float sh0 = coef[HF + lane * 2], sh1 = coef[HF + lane * 2 + 1];
    int s = starts[g], e = starts[g + 1];
    int len = e - s;
    int chunk = (len + 15) >> 4;
    int r0 = s + p * chunk;
    int r1 = min(e, r0 + chunk);
    float a0 = 0.f, a1 = 0.f;
    for (int r = r0; r < r1; ++r) {
        uintT v = *reinterpret_cast<const uintT*>(h + (size_t)r * HF + lane * 2);
        a0 += fmaxf(bf2f(v & 0xffff) * sc0 + sh0, 0.f);
        a1 += fmaxf(bf2f_hi(v) * sc1 + sh1, 0.f);
    }
    if (r1 > r0) {
        atomicAdd(&pooled[g * HF + lane * 2], a0);
        atomicAdd(&pooled[g * HF + lane * 2 + 1], a1);
    }
}

// ---------------- head ----------------

__global__ __launch_bounds__(1024) void head_kernel(const float* __restrict__ pooled,
                                                    const int* __restrict__ starts,
                                                    const float* __restrict__ Wl,
                                                    const float* __restrict__ bl,
                                                    const float* __restrict__ Wo,
                                                    const float* __restrict__ bo,
                                                    float* __restrict__ out) {
    __shared__ float P[NG][HF];
    __shared__ float T[NG][HF];
    int t = threadIdx.x;
    for (int i = t; i < NG * HF; i += 1024) {
        int g = i >> 7;
        float cnt = fmaxf((float)(starts[g + 1] - starts[g]), 1.0f);
        P[g][i & 127] = pooled[i] / cnt;
    }
    __syncthreads();
    for (int i = t; i < NG * HF; i += 1024) {
        int g = i >> 7, j = i & 127;
        float acc = bl[j];
        for (int k = 0; k < HF; ++k) acc += P[g][k] * Wl[k * HF + j];
        T[g][j] = fmaxf(acc, 0.f);
    }
    __syncthreads();
    int g = t >> 4, o = t & 15;
    float acc = bo[o];
    for (int k = 0; k < HF; ++k) acc += T[g][k] * Wo[k * OUTF + o];
    out[t] = acc;
}

// ---------------- launch ----------------

extern "C" void kernel_launch(void* const* d_in, const int* in_sizes, int n_in,
                              void* d_out, int out_size, void* d_ws, size_t ws_size,
                              hipStream_t stream) {
    const float* x     = (const float*)d_in[0];
    const int*   ei    = (const int*)d_in[1];
    const int*   batch = (const int*)d_in[2];
    const float* W0 = (const float*)d_in[3];
    const float* g0 = (const float*)d_in[5];
    const float* be0 = (const float*)d_in[6];
    const float* W1 = (const float*)d_in[7];
    const float* g1 = (const float*)d_in[9];
    const float* be1 = (const float*)d_in[10];
    const float* W2 = (const float*)d_in[11];
    const float* g2 = (const float*)d_in[13];
    const float* be2 = (const float*)d_in[14];
    const float* Wl = (const float*)d_in[15];
    const float* bl = (const float*)d_in[16];
    const float* Wo = (const float*)d_in[17];
    const float* bo = (const float*)d_in[18];

    const int n = in_sizes[0];
    const int E = in_sizes[1] / 2;
    const int* srcI = ei;
    const int* dstI = ei + E;
    const int PB = (n + NB - 1) / NB;       // 98 for n=100000; pack assumes PB<=256, n<2^18

    ushortT* bufA = (ushortT*)d_ws;                      // n*HF bf16
    ushortT* bufB = bufA + (size_t)n * HF;               // n*HF bf16
    float* dis    = (float*)(bufB + (size_t)n * HF);     // n
    float* xp     = dis + n;                             // n
    float* aggx   = xp + n;                              // n
    float* stats  = aggx + n;                            // 2*HF + 2
    float* coef   = stats + 2 * HF + 2;                  // 2*HF
    float* pooled = coef + 2 * HF;                       // NG*HF
    int* degi     = (int*)(pooled + NG * HF);            // n
    int* rowptr   = degi + n;                            // n+1
    int* bcur     = rowptr + n + 1;                      // NB
    int* csr_src  = bcur + NB;                           // E
    uintT* tmp    = (uintT*)(csr_src + E);               // E
    int* blocksums = (int*)(tmp + E);                    // 256
    int* starts   = blocksums + 256;                     // NG+1
    float* stats1 = stats + 2 * HF;                      // 2 scalars

    const int nbScan = (n + 1023) / 1024;

    // ---- CSR build: degree -> rowptr -> bucket scatter -> in-bucket reorder ----
    hipMemsetAsync(degi, 0, (size_t)n * 4, stream);
    degi_kernel<<<(E + 255) / 256, 256, 0, stream>>>(dstI, degi, E);
    dis_xp_kernel<<<(n + 255) / 256, 256, 0, stream>>>(degi, x, dis, xp, n);
    scan_partial<<<nbScan, 256, 0, stream>>>(degi, blocksums, n);
    scan_sums<<<1, 64, 0, stream>>>(blocksums, nbScan);
    scan_final<<<nbScan, 256, 0, stream>>>(degi, blocksums, rowptr, n);
    binit_kernel<<<(NB + 255) / 256, 256, 0, stream>>>(rowptr, bcur, n, PB);
    bucket_scatter_kernel<<<(E + 255) / 256, 256, 0, stream>>>(srcI, dstI, bcur, tmp, E, PB);
    bucket_reorder_kernel<<<NB, 256, 0, stream>>>(tmp, rowptr, csr_src, n, PB);

    // ---- layer 0 (rank-1) ----
    gather1_kernel<<<(n + 255) / 256, 256, 0, stream>>>(xp, rowptr, csr_src, dis, aggx, n);
    hipMemsetAsync(stats1, 0, 2 * 4, stream);
    stats1_kernel<<<256, 256, 0, stream>>>(aggx, stats1, n);
    coef0_kernel<<<1, 128, 0, stream>>>(stats1, W0, g0, be0, coef, 1.0f / n);
    h0_kernel<<<(n * 32 + 255) / 256, 256, 0, stream>>>(aggx, coef, bufA, n);

    // ---- layer 1 ----
    gemm128_kernel<<<(n + 15) / 16, 256, 0, stream>>>(bufA, W1, coef, dis, bufB, n, 0);
    gather128_kernel<<<(n * 64 + 255) / 256, 256, 0, stream>>>(bufB, rowptr, csr_src, dis, bufA, n);
    hipMemsetAsync(stats, 0, 2 * HF * 4, stream);
    bn_stats_kernel<<<512, 256, 0, stream>>>(bufA, stats, n);
    bn_coef_kernel<<<1, 128, 0, stream>>>(stats, g1, be1, coef, 1.0f / n);

    // ---- layer 2 ----
    gemm128_kernel<<<(n + 15) / 16, 256, 0, stream>>>(bufA, W2, coef, dis, bufB, n, 1);
    gather128_kernel<<<(n * 64 + 255) / 256, 256, 0, stream>>>(bufB, rowptr, csr_src, dis, bufA, n);
    hipMemsetAsync(stats, 0, 2 * HF * 4, stream);
    bn_stats_kernel<<<512, 256, 0, stream>>>(bufA, stats, n);
    bn_coef_kernel<<<1, 128, 0, stream>>>(stats, g2, be2, coef, 1.0f / n);

    // ---- pool (fused BN+ReLU) + head ----
    starts_kernel<<<1, 128, 0, stream>>>(batch, starts, n);
    hipMemsetAsync(pooled, 0, NG * HF * 4, stream);
    pool_kernel<<<NG * 16, 64, 0, stream>>>(bufA, coef, starts, pooled);
    head_kernel<<<1, 1024, 0, stream>>>(pooled, starts, Wl, bl, Wo, bo, (float*)d_out);
}

// Round 6
// 669.265 us; speedup vs baseline: 1.3937x; 1.3937x over previous
//
#include <hip/hip_runtime.h>

#define HF 128
#define OUTF 16
#define NG 64
#define NB 1024            // CSR build buckets; PB = ceil(n/NB) must be <= 256
#define CHUNK 16384        // edges per scatter block
#define BN_EPS 1e-5f

typedef unsigned short ushortT;
typedef unsigned int uintT;

__device__ __forceinline__ float bf2f(uintT u) {
    union { uintT i; float f; } c; c.i = u << 16; return c.f;
}
__device__ __forceinline__ float bf2f_hi(uintT u) {
    union { uintT i; float f; } c; c.i = u & 0xffff0000u; return c.f;
}
__device__ __forceinline__ uintT f2bf(float f) {
    union { float f; uintT i; } c; c.f = f;
    uintT u = c.i;
    return (u + 0x7fffu + ((u >> 16) & 1u)) >> 16;
}
__device__ __forceinline__ uintT pack2(float a, float b) {
    return f2bf(a) | (f2bf(b) << 16);
}

// ---------------- degree (int) / normalization ----------------

__global__ void degi_kernel(const int* __restrict__ dst, int* __restrict__ degi, int E) {
    int e = blockIdx.x * blockDim.x + threadIdx.x;
    if (e < E) atomicAdd(&degi[dst[e]], 1);
}

__global__ void dis_xp_kernel(const int* __restrict__ degi, const float* __restrict__ x,
                              float* __restrict__ dis, float* __restrict__ xp, int n) {
    int i = blockIdx.x * blockDim.x + threadIdx.x;
    if (i < n) {
        float d = rsqrtf((float)degi[i] + 1.0f);   // +1 = self loop
        dis[i] = d;
        xp[i] = d * x[i];
    }
}

// ---------------- prefix sum (rowptr over deg; no self-loop entries) ----------------

__global__ __launch_bounds__(256) void scan_partial(const int* __restrict__ degi,
                                                    int* __restrict__ blocksums, int n) {
    __shared__ int sdata[256];
    int b = blockIdx.x, t = threadIdx.x;
    int s = 0;
    for (int k = t; k < 1024; k += 256) {
        int i = b * 1024 + k;
        if (i < n) s += degi[i];
    }
    sdata[t] = s; __syncthreads();
    for (int o = 128; o > 0; o >>= 1) {
        if (t < o) sdata[t] += sdata[t + o];
        __syncthreads();
    }
    if (t == 0) blocksums[b] = sdata[0];
}

__global__ void scan_sums(int* __restrict__ blocksums, int nb) {
    if (threadIdx.x == 0) {
        int run = 0;
        for (int i = 0; i < nb; ++i) { int v = blocksums[i]; blocksums[i] = run; run += v; }
    }
}

__global__ __launch_bounds__(256) void scan_final(const int* __restrict__ degi,
                                                  const int* __restrict__ blocksums,
                                                  int* __restrict__ rowptr, int n) {
    int b = blockIdx.x, t = threadIdx.x;
    int base = b * 1024 + t * 4;
    int v[4]; int s = 0;
    for (int k = 0; k < 4; ++k) {
        int i = base + k;
        v[k] = (i < n) ? degi[i] : 0;
        s += v[k];
    }
    __shared__ int ts[256];
    ts[t] = s; __syncthreads();
    for (int o = 1; o < 256; o <<= 1) {
        int val = (t >= o) ? ts[t - o] : 0;
        __syncthreads();
        ts[t] += val;
        __syncthreads();
    }
    int off = blocksums[b] + ((t > 0) ? ts[t - 1] : 0);
    for (int k = 0; k < 4; ++k) {
        int i = base + k;
        if (i < n) {
            rowptr[i] = off;
            off += v[k];
            if (i == n - 1) rowptr[n] = off;
        }
    }
}

// ---------------- bucketed CSR build ----------------

__global__ void binit_kernel(const int* __restrict__ rowptr, int* __restrict__ bcur,
                             int n, int PB) {
    int b = blockIdx.x * blockDim.x + threadIdx.x;
    if (b < NB) bcur[b] = rowptr[min(b * PB, n)];
}

// Hierarchical scatter: per-block LDS histogram -> one global reserve per
// (block,bucket) -> LDS-cursor scatter. tmp[pos] = (local_dst << 18) | src.
__global__ __launch_bounds__(256) void hist_scatter_kernel(const int* __restrict__ src,
                                                           const int* __restrict__ dst,
                                                           int* __restrict__ bcur,
                                                           uintT* __restrict__ tmp,
                                                           int E, int PB) {
    __shared__ int hcount[NB];   // 4 KB: pass-1 histogram, then pass-2 cursor
    __shared__ int lbase[NB];    // 4 KB: reserved global base per bucket
    int t = threadIdx.x;
    int e0 = blockIdx.x * CHUNK;
    int e1 = min(E, e0 + CHUNK);
    for (int i = t; i < NB; i += 256) hcount[i] = 0;
    __syncthreads();
    for (int e = e0 + t; e < e1; e += 256) {
        int b = dst[e] / PB;
        atomicAdd(&hcount[b], 1);
    }
    __syncthreads();
    for (int i = t; i < NB; i += 256) {
        int c = hcount[i];
        lbase[i] = (c > 0) ? atomicAdd(&bcur[i], c) : 0;
    }
    __syncthreads();
    for (int i = t; i < NB; i += 256) hcount[i] = 0;
    __syncthreads();
    for (int e = e0 + t; e < e1; e += 256) {
        int d = dst[e];
        int b = d / PB;
        int pos = lbase[b] + atomicAdd(&hcount[b], 1);
        tmp[pos] = ((uintT)(d - b * PB) << 18) | (uintT)src[e];
    }
}

__global__ __launch_bounds__(256) void bucket_reorder_kernel(const uintT* __restrict__ tmp,
                                                             const int* __restrict__ rowptr,
                                                             int* __restrict__ csr_src,
                                                             int n, int PB) {
    __shared__ int lcur[256];          // PB <= 256
    __shared__ int stage[4096];
    int b = blockIdx.x;
    int n0 = b * PB;
    if (n0 >= n) return;
    int n1 = min(n0 + PB, n);
    int t = threadIdx.x;
    int start = rowptr[n0], end = rowptr[n1];
    int cnt = end - start;
    for (int i = t; i < n1 - n0; i += 256) lcur[i] = rowptr[n0 + i] - start;
    __syncthreads();
    if (cnt <= 4096) {
        for (int i = t; i < cnt; i += 256) {
            uintT p = tmp[start + i];
            int ldst = p >> 18;
            int pos = atomicAdd(&lcur[ldst], 1);
            stage[pos] = (int)(p & 0x3ffffu);
        }
        __syncthreads();
        for (int i = t; i < cnt; i += 256) csr_src[start + i] = stage[i];
    } else {
        for (int i = t; i < cnt; i += 256) {
            uintT p = tmp[start + i];
            int ldst = p >> 18;
            int pos = atomicAdd(&lcur[ldst], 1);
            csr_src[start + pos] = (int)(p & 0x3ffffu);
        }
    }
}

// ---------------- layer 0: scalar gather (xp = dis*x) ----------------

__global__ void gather1_kernel(const float* __restrict__ xp, const int* __restrict__ rowptr,
                               const int* __restrict__ csr_src, const float* __restrict__ dis,
                               float* __restrict__ aggx, int n) {
    int i = blockIdx.x * blockDim.x + threadIdx.x;
    if (i >= n) return;
    float acc = xp[i];                // self loop
    int e = rowptr[i + 1];
    for (int j = rowptr[i]; j < e; ++j) acc += xp[csr_src[j]];
    aggx[i] = acc * dis[i];
}

__global__ void stats1_kernel(const float* __restrict__ aggx, float* __restrict__ stats1, int n) {
    float s = 0.f, ss = 0.f;
    for (int i = blockIdx.x * blockDim.x + threadIdx.x; i < n; i += gridDim.x * blockDim.x) {
        float v = aggx[i]; s += v; ss += v * v;
    }
    for (int o = 32; o > 0; o >>= 1) { s += __shfl_down(s, o); ss += __shfl_down(ss, o); }
    if ((threadIdx.x & 63) == 0) { atomicAdd(&stats1[0], s); atomicAdd(&stats1[1], ss); }
}

__global__ void coef0_kernel(const float* __restrict__ stats1, const float* __restrict__ W0,
                             const float* __restrict__ g, const float* __restrict__ beta,
                             float* __restrict__ coef, float invn) {
    int j = threadIdx.x;
    if (j < HF) {
        float m = stats1[0] * invn;
        float var = stats1[1] * invn - m * m;
        float w = W0[j];
        float sc = g[j] * w * rsqrtf(var * w * w + BN_EPS);
        coef[j] = sc;
        coef[HF + j] = beta[j] - m * sc;
    }
}

__global__ void h0_kernel(const float* __restrict__ aggx, const float* __restrict__ coef,
                          ushortT* __restrict__ h0, int n) {
    int idx = blockIdx.x * blockDim.x + threadIdx.x;
    if (idx >= n * (HF / 4)) return;
    int i = idx >> 5, jc = idx & 31;
    float a = aggx[i];
    float4 sc = reinterpret_cast<const float4*>(coef)[jc];
    float4 sh = reinterpret_cast<const float4*>(coef + HF)[jc];
    float o0 = fmaxf(a * sc.x + sh.x, 0.f);
    float o1 = fmaxf(a * sc.y + sh.y, 0.f);
    float o2 = fmaxf(a * sc.z + sh.z, 0.f);
    float o3 = fmaxf(a * sc.w + sh.w, 0.f);
    uint2 o; o.x = pack2(o0, o1); o.y = pack2(o2, o3);
    reinterpret_cast<uint2*>(h0)[idx] = o;
}

// ---------------- GEMM: C[n,128] = dis[row] * (act(A)[n,128] @ W[128,128]) ----------------

__global__ __launch_bounds__(256) void gemm128_kernel(const ushortT* __restrict__ A,
                                                      const float* __restrict__ W,
                                                      const float* __restrict__ coef,
                                                      const float* __restrict__ dis,
                                                      ushortT* __restrict__ C, int n,
                                                      int applyCoef) {
    __shared__ float Ws[128 * 128];
    __shared__ float As[16][128];
    int t = threadIdx.x;
    for (int i = t; i < 128 * 128; i += 256) Ws[i] = W[i];
    int rowBase = blockIdx.x * 16;
    for (int i = t; i < 16 * 32; i += 256) {
        int rr = i >> 5, g = i & 31;
        int r = rowBase + rr;
        uint2 v = make_uint2(0u, 0u);
        if (r < n) v = *reinterpret_cast<const uint2*>(A + (size_t)r * HF + g * 4);
        float f0 = bf2f(v.x & 0xffff), f1 = bf2f_hi(v.x);
        float f2 = bf2f(v.y & 0xffff), f3 = bf2f_hi(v.y);
        if (applyCoef) {
            int c = g * 4;
            f0 = fmaxf(f0 * coef[c + 0] + coef[HF + c + 0], 0.f);
            f1 = fmaxf(f1 * coef[c + 1] + coef[HF + c + 1], 0.f);
            f2 = fmaxf(f2 * coef[c + 2] + coef[HF + c + 2], 0.f);
            f3 = fmaxf(f3 * coef[c + 3] + coef[HF + c + 3], 0.f);
        }
        As[rr][g * 4 + 0] = f0;
        As[rr][g * 4 + 1] = f1;
        As[rr][g * 4 + 2] = f2;
        As[rr][g * 4 + 3] = f3;
    }
    __syncthreads();
    int jc = t & 31;
    int rs = t >> 5;
    float4 acc0 = {0, 0, 0, 0}, acc1 = {0, 0, 0, 0};
    for (int k = 0; k < 128; ++k) {
        float4 w = reinterpret_cast<const float4*>(Ws + k * 128)[jc];
        float a0 = As[rs][k], a1 = As[rs + 8][k];
        acc0.x += a0 * w.x; acc0.y += a0 * w.y; acc0.z += a0 * w.z; acc0.w += a0 * w.w;
        acc1.x += a1 * w.x; acc1.y += a1 * w.y; acc1.z += a1 * w.z; acc1.w += a1 * w.w;
    }
    int r0 = rowBase + rs, r1 = r0 + 8;
    if (r0 < n) {
        float d0 = dis[r0];
        uint2 o; o.x = pack2(acc0.x * d0, acc0.y * d0); o.y = pack2(acc0.z * d0, acc0.w * d0);
        *reinterpret_cast<uint2*>(C + (size_t)r0 * HF + jc * 4) = o;
    }
    if (r1 < n) {
        float d1 = dis[r1];
        uint2 o; o.x = pack2(acc1.x * d1, acc1.y * d1); o.y = pack2(acc1.z * d1, acc1.w * d1);
        *reinterpret_cast<uint2*>(C + (size_t)r1 * HF + jc * 4) = o;
    }
}

// ---------------- CSR gather: agg[d] = dis[d]*(sum src rows + own row) ----------------

__global__ __launch_bounds__(256) void gather128_kernel(const ushortT* __restrict__ h2,
                                                        const int* __restrict__ rowptr,
                                                        const int* __restrict__ csr_src,
                                                        const float* __restrict__ dis,
                                                        ushortT* __restrict__ agg, int n) {
    int node = (blockIdx.x * 256 + threadIdx.x) >> 6;
    int lane = threadIdx.x & 63;
    if (node >= n) return;
    int beg = rowptr[node], end = rowptr[node + 1];
    uintT vs = *reinterpret_cast<const uintT*>(h2 + (size_t)node * HF + lane * 2);
    float a0 = bf2f(vs & 0xffff), a1 = bf2f_hi(vs);
    for (int base = beg; base < end; base += 64) {
        int idx = base + lane;
        int sj = (idx < end) ? csr_src[idx] : 0;
        int cnt = min(64, end - base);
        int j = 0;
        for (; j + 4 <= cnt; j += 4) {
            int s0 = __shfl(sj, j);
            int s1 = __shfl(sj, j + 1);
            int s2 = __shfl(sj, j + 2);
            int s3 = __shfl(sj, j + 3);
            uintT v0 = *reinterpret_cast<const uintT*>(h2 + (size_t)s0 * HF + lane * 2);
            uintT v1 = *reinterpret_cast<const uintT*>(h2 + (size_t)s1 * HF + lane * 2);
            uintT v2 = *reinterpret_cast<const uintT*>(h2 + (size_t)s2 * HF + lane * 2);
            uintT v3 = *reinterpret_cast<const uintT*>(h2 + (size_t)s3 * HF + lane * 2);
            a0 += bf2f(v0 & 0xffff); a1 += bf2f_hi(v0);
            a0 += bf2f(v1 & 0xffff); a1 += bf2f_hi(v1);
            a0 += bf2f(v2 & 0xffff); a1 += bf2f_hi(v2);
            a0 += bf2f(v3 & 0xffff); a1 += bf2f_hi(v3);
        }
        for (; j < cnt; ++j) {
            int s = __shfl(sj, j);
            uintT v = *reinterpret_cast<const uintT*>(h2 + (size_t)s * HF + lane * 2);
            a0 += bf2f(v & 0xffff); a1 += bf2f_hi(v);
        }
    }
    float dd = dis[node];
    *reinterpret_cast<uintT*>(agg + (size_t)node * HF + lane * 2) = pack2(a0 * dd, a1 * dd);
}

// ---------------- BN stats / coef ----------------

__global__ __launch_bounds__(256) void bn_stats_kernel(const ushortT* __restrict__ a,
                                                       float* __restrict__ stats, int n) {
    int lane = threadIdx.x & 63;
    int sub = threadIdx.x >> 6;
    float s0 = 0.f, s1 = 0.f, ss0 = 0.f, ss1 = 0.f;
    for (int r = blockIdx.x * 4 + sub; r < n; r += gridDim.x * 4) {
        uintT v = *reinterpret_cast<const uintT*>(a + (size_t)r * HF + lane * 2);
        float x0 = bf2f(v & 0xffff), x1 = bf2f_hi(v);
        s0 += x0; ss0 += x0 * x0;
        s1 += x1; ss1 += x1 * x1;
    }
    __shared__ float red[4][4][64];
    red[0][sub][lane] = s0; red[1][sub][lane] = s1;
    red[2][sub][lane] = ss0; red[3][sub][lane] = ss1;
    __syncthreads();
    if (sub == 0) {
        float S0 = red[0][0][lane] + red[0][1][lane] + red[0][2][lane] + red[0][3][lane];
        float S1 = red[1][0][lane] + red[1][1][lane] + red[1][2][lane] + red[1][3][lane];
        float T0 = red[2][0][lane] + red[2][1][lane] + red[2][2][lane] + red[2][3][lane];
        float T1 = red[3][0][lane] + red[3][1][lane] + red[3][2][lane] + red[3][3][lane];
        atomicAdd(&stats[lane * 2], S0);
        atomicAdd(&stats[lane * 2 + 1], S1);
        atomicAdd(&stats[HF + lane * 2], T0);
        atomicAdd(&stats[HF + lane * 2 + 1], T1);
    }
}

__global__ void bn_coef_kernel(const float* __restrict__ stats, const float* __restrict__ g,
                               const float* __restrict__ beta, float* __restrict__ coef,
                               float invn) {
    int j = threadIdx.x;
    if (j < HF) {
        float m = stats[j] * invn;
        float v = stats[HF + j] * invn - m * m;
        float sc = g[j] * rsqrtf(v + BN_EPS);
        coef[j] = sc;
        coef[HF + j] = beta[j] - m * sc;
    }
}

// ---------------- pooling (fused BN+ReLU of layer 2) ----------------

__global__ void starts_kernel(const int* __restrict__ batch, int* __restrict__ starts, int n) {
    int g = threadIdx.x;
    if (g > NG) return;
    int lo = 0, hi = n;
    while (lo < hi) {
        int mid = (lo + hi) >> 1;
        if (batch[mid] < g) lo = mid + 1; else hi = mid;
    }
    starts[g] = lo;
}

__global__ void pool_kernel(const ushortT* __restrict__ h, const float* __restrict__ coef,
                            const int* __restrict__ starts, float* __restrict__ pooled) {
    int g = blockIdx.x >> 4;
    int p = blockIdx.x & 15;
    int lane = threadIdx.x;
    float sc0 = coef[lane * 2],     sc1 = coef[lane * 2 + 1];
    float sh0 = coef[HF + lane * 2], sh1 = coef[HF + lane * 2 + 1];
    int s = starts[g], e = starts[g + 1];
    int len = e - s;
    int chunk = (len + 15) >> 4;
    int r0 = s + p * chunk;
    int r1 = min(e, r0 + chunk);
    float a0 = 0.f, a1 = 0.f;
    for (int r = r0; r < r1; ++r) {
        uintT v = *reinterpret_cast<const uintT*>(h + (size_t)r * HF + lane * 2);
        a0 += fmaxf(bf2f(v & 0xffff) * sc0 + sh0, 0.f);
        a1 += fmaxf(bf2f_hi(v) * sc1 + sh1, 0.f);
    }
    if (r1 > r0) {
        atomicAdd(&pooled[g * HF + lane * 2], a0);
        atomicAdd(&pooled[g * HF + lane * 2 + 1], a1);
    }
}

// ---------------- head ----------------

__global__ __launch_bounds__(1024) void head_kernel(const float* __restrict__ pooled,
                                                    const int* __restrict__ starts,
                                                    const float* __restrict__ Wl,
                                                    const float* __restrict__ bl,
                                                    const float* __restrict__ Wo,
                                                    const float* __restrict__ bo,
                                                    float* __restrict__ out) {
    __shared__ float P[NG][HF];
    __shared__ float T[NG][HF];
    int t = threadIdx.x;
    for (int i = t; i < NG * HF; i += 1024) {
        int g = i >> 7;
        float cnt = fmaxf((float)(starts[g + 1] - starts[g]), 1.0f);
        P[g][i & 127] = pooled[i] / cnt;
    }
    __syncthreads();
    for (int i = t; i < NG * HF; i += 1024) {
        int g = i >> 7, j = i & 127;
        float acc = bl[j];
        for (int k = 0; k < HF; ++k) acc += P[g][k] * Wl[k * HF + j];
        T[g][j] = fmaxf(acc, 0.f);
    }
    __syncthreads();
    int g = t >> 4, o = t & 15;
    float acc = bo[o];
    for (int k = 0; k < HF; ++k) acc += T[g][k] * Wo[k * OUTF + o];
    out[t] = acc;
}

// ---------------- launch ----------------

extern "C" void kernel_launch(void* const* d_in, const int* in_sizes, int n_in,
                              void* d_out, int out_size, void* d_ws, size_t ws_size,
                              hipStream_t stream) {
    const float* x     = (const float*)d_in[0];
    const int*   ei    = (const int*)d_in[1];
    const int*   batch = (const int*)d_in[2];
    const float* W0 = (const float*)d_in[3];
    const float* g0 = (const float*)d_in[5];
    const float* be0 = (const float*)d_in[6];
    const float* W1 = (const float*)d_in[7];
    const float* g1 = (const float*)d_in[9];
    const float* be1 = (const float*)d_in[10];
    const float* W2 = (const float*)d_in[11];
    const float* g2 = (const float*)d_in[13];
    const float* be2 = (const float*)d_in[14];
    const float* Wl = (const float*)d_in[15];
    const float* bl = (const float*)d_in[16];
    const float* Wo = (const float*)d_in[17];
    const float* bo = (const float*)d_in[18];

    const int n = in_sizes[0];
    const int E = in_sizes[1] / 2;
    const int* srcI = ei;
    const int* dstI = ei + E;
    const int PB = (n + NB - 1) / NB;       // 98 for n=100000; pack assumes PB<=256, n<2^18

    ushortT* bufA = (ushortT*)d_ws;                      // n*HF bf16
    ushortT* bufB = bufA + (size_t)n * HF;               // n*HF bf16
    float* dis    = (float*)(bufB + (size_t)n * HF);     // n
    float* xp     = dis + n;                             // n
    float* aggx   = xp + n;                              // n
    float* stats  = aggx + n;                            // 2*HF + 2
    float* coef   = stats + 2 * HF + 2;                  // 2*HF
    float* pooled = coef + 2 * HF;                       // NG*HF
    int* degi     = (int*)(pooled + NG * HF);            // n
    int* rowptr   = degi + n;                            // n+1
    int* bcur     = rowptr + n + 1;                      // NB
    int* csr_src  = bcur + NB;                           // E
    uintT* tmp    = (uintT*)(csr_src + E);               // E
    int* blocksums = (int*)(tmp + E);                    // 256
    int* starts   = blocksums + 256;                     // NG+1
    float* stats1 = stats + 2 * HF;                      // 2 scalars

    const int nbScan = (n + 1023) / 1024;
    const int nbChunk = (E + CHUNK - 1) / CHUNK;

    // ---- CSR build: degree -> rowptr -> hierarchical bucket scatter -> reorder ----
    hipMemsetAsync(degi, 0, (size_t)n * 4, stream);
    degi_kernel<<<(E + 255) / 256, 256, 0, stream>>>(dstI, degi, E);
    dis_xp_kernel<<<(n + 255) / 256, 256, 0, stream>>>(degi, x, dis, xp, n);
    scan_partial<<<nbScan, 256, 0, stream>>>(degi, blocksums, n);
    scan_sums<<<1, 64, 0, stream>>>(blocksums, nbScan);
    scan_final<<<nbScan, 256, 0, stream>>>(degi, blocksums, rowptr, n);
    binit_kernel<<<(NB + 255) / 256, 256, 0, stream>>>(rowptr, bcur, n, PB);
    hist_scatter_kernel<<<nbChunk, 256, 0, stream>>>(srcI, dstI, bcur, tmp, E, PB);
    bucket_reorder_kernel<<<NB, 256, 0, stream>>>(tmp, rowptr, csr_src, n, PB);

    // ---- layer 0 (rank-1) ----
    gather1_kernel<<<(n + 255) / 256, 256, 0, stream>>>(xp, rowptr, csr_src, dis, aggx, n);
    hipMemsetAsync(stats1, 0, 2 * 4, stream);
    stats1_kernel<<<256, 256, 0, stream>>>(aggx, stats1, n);
    coef0_kernel<<<1, 128, 0, stream>>>(stats1, W0, g0, be0, coef, 1.0f / n);
    h0_kernel<<<(n * 32 + 255) / 256, 256, 0, stream>>>(aggx, coef, bufA, n);

    // ---- layer 1 ----
    gemm128_kernel<<<(n + 15) / 16, 256, 0, stream>>>(bufA, W1, coef, dis, bufB, n, 0);
    gather128_kernel<<<(n * 64 + 255) / 256, 256, 0, stream>>>(bufB, rowptr, csr_src, dis, bufA, n);
    hipMemsetAsync(stats, 0, 2 * HF * 4, stream);
    bn_stats_kernel<<<512, 256, 0, stream>>>(bufA, stats, n);
    bn_coef_kernel<<<1, 128, 0, stream>>>(stats, g1, be1, coef, 1.0f / n);

    // ---- layer 2 ----
    gemm128_kernel<<<(n + 15) / 16, 256, 0, stream>>>(bufA, W2, coef, dis, bufB, n, 1);
    gather128_kernel<<<(n * 64 + 255) / 256, 256, 0, stream>>>(bufB, rowptr, csr_src, dis, bufA, n);
    hipMemsetAsync(stats, 0, 2 * HF * 4, stream);
    bn_stats_kernel<<<512, 256, 0, stream>>>(bufA, stats, n);
    bn_coef_kernel<<<1, 128, 0, stream>>>(stats, g2, be2, coef, 1.0f / n);

    // ---- pool (fused BN+ReLU) + head ----
    starts_kernel<<<1, 128, 0, stream>>>(batch, starts, n);
    hipMemsetAsync(pooled, 0, NG * HF * 4, stream);
    pool_kernel<<<NG * 16, 64, 0, stream>>>(bufA, coef, starts, pooled);
    head_kernel<<<1, 1024, 0, stream>>>(pooled, starts, Wl, bl, Wo, bo, (float*)d_out);
}

// Round 7
// 547.263 us; speedup vs baseline: 1.7043x; 1.2229x over previous
//
#include <hip/hip_runtime.h>

#define HF 128
#define OUTF 16
#define NG 64
#define NB 1024            // CSR build buckets; PB = ceil(n/NB) must be <= 256
#define CHUNK 16384        // edges per scatter block
#define BN_EPS 1e-5f

typedef unsigned short ushortT;
typedef unsigned int uintT;
typedef __attribute__((ext_vector_type(8))) short bf16x8;
typedef __attribute__((ext_vector_type(4))) float f32x4;

__device__ __forceinline__ float bf2f(uintT u) {
    union { uintT i; float f; } c; c.i = u << 16; return c.f;
}
__device__ __forceinline__ float bf2f_hi(uintT u) {
    union { uintT i; float f; } c; c.i = u & 0xffff0000u; return c.f;
}
__device__ __forceinline__ uintT f2bf(float f) {
    union { float f; uintT i; } c; c.f = f;
    uintT u = c.i;
    return (u + 0x7fffu + ((u >> 16) & 1u)) >> 16;
}
__device__ __forceinline__ uintT pack2(float a, float b) {
    return f2bf(a) | (f2bf(b) << 16);
}

// ---------------- degree (int) / normalization ----------------

__global__ void degi_kernel(const int* __restrict__ dst, int* __restrict__ degi, int E) {
    int e = blockIdx.x * blockDim.x + threadIdx.x;
    if (e < E) atomicAdd(&degi[dst[e]], 1);
}

__global__ void dis_xp_kernel(const int* __restrict__ degi, const float* __restrict__ x,
                              float* __restrict__ dis, float* __restrict__ xp, int n) {
    int i = blockIdx.x * blockDim.x + threadIdx.x;
    if (i < n) {
        float d = rsqrtf((float)degi[i] + 1.0f);   // +1 = self loop
        dis[i] = d;
        xp[i] = d * x[i];
    }
}

// ---------------- prefix sum (rowptr over deg; no self-loop entries) ----------------

__global__ __launch_bounds__(256) void scan_partial(const int* __restrict__ degi,
                                                    int* __restrict__ blocksums, int n) {
    __shared__ int sdata[256];
    int b = blockIdx.x, t = threadIdx.x;
    int s = 0;
    for (int k = t; k < 1024; k += 256) {
        int i = b * 1024 + k;
        if (i < n) s += degi[i];
    }
    sdata[t] = s; __syncthreads();
    for (int o = 128; o > 0; o >>= 1) {
        if (t < o) sdata[t] += sdata[t + o];
        __syncthreads();
    }
    if (t == 0) blocksums[b] = sdata[0];
}

__global__ void scan_sums(int* __restrict__ blocksums, int nb) {
    if (threadIdx.x == 0) {
        int run = 0;
        for (int i = 0; i < nb; ++i) { int v = blocksums[i]; blocksums[i] = run; run += v; }
    }
}

__global__ __launch_bounds__(256) void scan_final(const int* __restrict__ degi,
                                                  const int* __restrict__ blocksums,
                                                  int* __restrict__ rowptr, int n) {
    int b = blockIdx.x, t = threadIdx.x;
    int base = b * 1024 + t * 4;
    int v[4]; int s = 0;
    for (int k = 0; k < 4; ++k) {
        int i = base + k;
        v[k] = (i < n) ? degi[i] : 0;
        s += v[k];
    }
    __shared__ int ts[256];
    ts[t] = s; __syncthreads();
    for (int o = 1; o < 256; o <<= 1) {
        int val = (t >= o) ? ts[t - o] : 0;
        __syncthreads();
        ts[t] += val;
        __syncthreads();
    }
    int off = blocksums[b] + ((t > 0) ? ts[t - 1] : 0);
    for (int k = 0; k < 4; ++k) {
        int i = base + k;
        if (i < n) {
            rowptr[i] = off;
            off += v[k];
            if (i == n - 1) rowptr[n] = off;
        }
    }
}

// ---------------- bucketed CSR build ----------------

__global__ void binit_kernel(const int* __restrict__ rowptr, int* __restrict__ bcur,
                             int n, int PB) {
    int b = blockIdx.x * blockDim.x + threadIdx.x;
    if (b < NB) bcur[b] = rowptr[min(b * PB, n)];
}

// Hierarchical scatter: per-block LDS histogram -> one global reserve per
// (block,bucket) -> LDS-cursor scatter. tmp[pos] = (local_dst << 18) | src.
__global__ __launch_bounds__(256) void hist_scatter_kernel(const int* __restrict__ src,
                                                           const int* __restrict__ dst,
                                                           int* __restrict__ bcur,
                                                           uintT* __restrict__ tmp,
                                                           int E, int PB) {
    __shared__ int hcount[NB];
    __shared__ int lbase[NB];
    int t = threadIdx.x;
    int e0 = blockIdx.x * CHUNK;
    int e1 = min(E, e0 + CHUNK);
    for (int i = t; i < NB; i += 256) hcount[i] = 0;
    __syncthreads();
    for (int e = e0 + t; e < e1; e += 256) {
        int b = dst[e] / PB;
        atomicAdd(&hcount[b], 1);
    }
    __syncthreads();
    for (int i = t; i < NB; i += 256) {
        int c = hcount[i];
        lbase[i] = (c > 0) ? atomicAdd(&bcur[i], c) : 0;
    }
    __syncthreads();
    for (int i = t; i < NB; i += 256) hcount[i] = 0;
    __syncthreads();
    for (int e = e0 + t; e < e1; e += 256) {
        int d = dst[e];
        int b = d / PB;
        int pos = lbase[b] + atomicAdd(&hcount[b], 1);
        tmp[pos] = ((uintT)(d - b * PB) << 18) | (uintT)src[e];
    }
}

__global__ __launch_bounds__(256) void bucket_reorder_kernel(const uintT* __restrict__ tmp,
                                                             const int* __restrict__ rowptr,
                                                             int* __restrict__ csr_src,
                                                             int n, int PB) {
    __shared__ int lcur[256];          // PB <= 256
    __shared__ int stage[4096];
    int b = blockIdx.x;
    int n0 = b * PB;
    if (n0 >= n) return;
    int n1 = min(n0 + PB, n);
    int t = threadIdx.x;
    int start = rowptr[n0], end = rowptr[n1];
    int cnt = end - start;
    for (int i = t; i < n1 - n0; i += 256) lcur[i] = rowptr[n0 + i] - start;
    __syncthreads();
    if (cnt <= 4096) {
        for (int i = t; i < cnt; i += 256) {
            uintT p = tmp[start + i];
            int ldst = p >> 18;
            int pos = atomicAdd(&lcur[ldst], 1);
            stage[pos] = (int)(p & 0x3ffffu);
        }
        __syncthreads();
        for (int i = t; i < cnt; i += 256) csr_src[start + i] = stage[i];
    } else {
        for (int i = t; i < cnt; i += 256) {
            uintT p = tmp[start + i];
            int ldst = p >> 18;
            int pos = atomicAdd(&lcur[ldst], 1);
            csr_src[start + pos] = (int)(p & 0x3ffffu);
        }
    }
}

// ---------------- layer 0: scalar gather (xp = dis*x) ----------------

__global__ void gather1_kernel(const float* __restrict__ xp, const int* __restrict__ rowptr,
                               const int* __restrict__ csr_src, const float* __restrict__ dis,
                               float* __restrict__ aggx, int n) {
    int i = blockIdx.x * blockDim.x + threadIdx.x;
    if (i >= n) return;
    float acc = xp[i];                // self loop
    int e = rowptr[i + 1];
    for (int j = rowptr[i]; j < e; ++j) acc += xp[csr_src[j]];
    aggx[i] = acc * dis[i];
}

__global__ void stats1_kernel(const float* __restrict__ aggx, float* __restrict__ stats1, int n) {
    float s = 0.f, ss = 0.f;
    for (int i = blockIdx.x * blockDim.x + threadIdx.x; i < n; i += gridDim.x * blockDim.x) {
        float v = aggx[i]; s += v; ss += v * v;
    }
    for (int o = 32; o > 0; o >>= 1) { s += __shfl_down(s, o); ss += __shfl_down(ss, o); }
    if ((threadIdx.x & 63) == 0) { atomicAdd(&stats1[0], s); atomicAdd(&stats1[1], ss); }
}

__global__ void coef0_kernel(const float* __restrict__ stats1, const float* __restrict__ W0,
                             const float* __restrict__ g, const float* __restrict__ beta,
                             float* __restrict__ coef, float invn) {
    int j = threadIdx.x;
    if (j < HF) {
        float m = stats1[0] * invn;
        float var = stats1[1] * invn - m * m;
        float w = W0[j];
        float sc = g[j] * w * rsqrtf(var * w * w + BN_EPS);
        coef[j] = sc;
        coef[HF + j] = beta[j] - m * sc;
    }
}

__global__ void h0_kernel(const float* __restrict__ aggx, const float* __restrict__ coef,
                          ushortT* __restrict__ h0, int n) {
    int idx = blockIdx.x * blockDim.x + threadIdx.x;
    if (idx >= n * (HF / 4)) return;
    int i = idx >> 5, jc = idx & 31;
    float a = aggx[i];
    float4 sc = reinterpret_cast<const float4*>(coef)[jc];
    float4 sh = reinterpret_cast<const float4*>(coef + HF)[jc];
    float o0 = fmaxf(a * sc.x + sh.x, 0.f);
    float o1 = fmaxf(a * sc.y + sh.y, 0.f);
    float o2 = fmaxf(a * sc.z + sh.z, 0.f);
    float o3 = fmaxf(a * sc.w + sh.w, 0.f);
    uint2 o; o.x = pack2(o0, o1); o.y = pack2(o2, o3);
    reinterpret_cast<uint2*>(h0)[idx] = o;
}

// ---------------- MFMA GEMM: C[n,128] = dis[row] * (act(A)[n,128] @ W[128,128]) ----------------
// 4 waves/block, 64 rows/block. Wave: 16 rows x 128 cols, 8 col-tiles of 16x16,
// K=128 via 4x mfma_f32_16x16x32_bf16 per tile. Wt (transposed W, bf16) in LDS
// with 16B-slot XOR swizzle. applyCoef: relu(v*coef+shift) on A during unpack.

__global__ __launch_bounds__(256) void gemm_mfma_kernel(const ushortT* __restrict__ A,
                                                        const float* __restrict__ W,
                                                        const float* __restrict__ coef,
                                                        const float* __restrict__ dis,
                                                        ushortT* __restrict__ C, int n,
                                                        int applyCoef) {
    __shared__ ushortT Wt[128 * 128];   // 32 KB, Wt[col][k] bf16, swizzled
    int t = threadIdx.x;
    int wave = t >> 6, lane = t & 63;
    int l4 = lane >> 4;                  // 0..3 quarter-wave
    int lm = lane & 15;

    // stage Wt: i = k*128 + j  ->  row j, byte (k*2)^((j&7)<<4)
    for (int i = t; i < 128 * 128; i += 256) {
        int k = i >> 7, j = i & 127;
        int byteoff = (j << 8) + ((k << 1) ^ ((j & 7) << 4));
        *(ushortT*)((char*)Wt + byteoff) = (ushortT)f2bf(W[i]);
    }
    __syncthreads();

    int rowBase = blockIdx.x * 64 + wave * 16;
    int ar = rowBase + lm;                   // A-operand row for this lane
    int arc = min(ar, n - 1);                // clamp (garbage rows never stored)

    // load 4 A fragments (8 consecutive k each)
    bf16x8 af[4];
    #pragma unroll
    for (int kb = 0; kb < 4; ++kb) {
        int k0 = kb * 32 + l4 * 8;
        bf16x8 v = *reinterpret_cast<const bf16x8*>(A + (size_t)arc * HF + k0);
        if (applyCoef) {
            float4 sc0 = *reinterpret_cast<const float4*>(coef + k0);
            float4 sc1 = *reinterpret_cast<const float4*>(coef + k0 + 4);
            float4 sh0 = *reinterpret_cast<const float4*>(coef + HF + k0);
            float4 sh1 = *reinterpret_cast<const float4*>(coef + HF + k0 + 4);
            const float* scp = (const float*)&sc0;   // sc0,sc1 contiguous? use arrays
            float scv[8] = {sc0.x, sc0.y, sc0.z, sc0.w, sc1.x, sc1.y, sc1.z, sc1.w};
            float shv[8] = {sh0.x, sh0.y, sh0.z, sh0.w, sh1.x, sh1.y, sh1.z, sh1.w};
            (void)scp;
            bf16x8 o;
            #pragma unroll
            for (int j = 0; j < 8; ++j) {
                float f = bf2f((uintT)(ushortT)v[j]);
                f = fmaxf(f * scv[j] + shv[j], 0.f);
                o[j] = (short)f2bf(f);
            }
            v = o;
        }
        af[kb] = v;
    }

    f32x4 acc[8];
    #pragma unroll
    for (int ct = 0; ct < 8; ++ct) acc[ct] = (f32x4){0.f, 0.f, 0.f, 0.f};

    #pragma unroll
    for (int ct = 0; ct < 8; ++ct) {
        int col = ct * 16 + lm;
        int rowbyte = col << 8;
        int swz = (col & 7) << 4;
        #pragma unroll
        for (int kb = 0; kb < 4; ++kb) {
            int off = ((kb * 64 + l4 * 16) ^ swz);
            bf16x8 bf = *reinterpret_cast<const bf16x8*>((const char*)Wt + rowbyte + off);
            acc[ct] = __builtin_amdgcn_mfma_f32_16x16x32_bf16(af[kb], bf, acc[ct], 0, 0, 0);
        }
    }

    // epilogue: D row = rbase + r, col = ct*16 + lm
    int rbase = rowBase + l4 * 4;
    float4 d4 = *reinterpret_cast<const float4*>(dis + min(rbase, n - 4));
    // careful: only valid if rbase <= n-4; re-read exact when clamped
    if (rbase > n - 4) {
        float tmp4[4];
        #pragma unroll
        for (int r = 0; r < 4; ++r) tmp4[r] = (rbase + r < n) ? dis[rbase + r] : 0.f;
        d4 = make_float4(tmp4[0], tmp4[1], tmp4[2], tmp4[3]);
    }
    const float* dd = (const float*)&d4;
    #pragma unroll
    for (int ct = 0; ct < 8; ++ct) {
        #pragma unroll
        for (int r = 0; r < 4; ++r) {
            float v = acc[ct][r] * dd[r];
            float o = __shfl_xor(v, 1);
            int row = rbase + r;
            if ((lane & 1) == 0 && row < n) {
                *(uintT*)(C + (size_t)row * HF + ct * 16 + lm) = pack2(v, o);
            }
        }
    }
}

// ---------------- CSR gather: agg[d] = dis[d]*(sum src rows + own row) ----------------

__global__ __launch_bounds__(256) void gather128_kernel(const ushortT* __restrict__ h2,
                                                        const int* __restrict__ rowptr,
                                                        const int* __restrict__ csr_src,
                                                        const float* __restrict__ dis,
                                                        ushortT* __restrict__ agg, int n) {
    int node = (blockIdx.x * 256 + threadIdx.x) >> 6;
    int lane = threadIdx.x & 63;
    if (node >= n) return;
    int beg = rowptr[node], end = rowptr[node + 1];
    uintT vs = *reinterpret_cast<const uintT*>(h2 + (size_t)node * HF + lane * 2);
    float a0 = bf2f(vs & 0xffff), a1 = bf2f_hi(vs);
    for (int base = beg; base < end; base += 64) {
        int idx = base + lane;
        int sj = (idx < end) ? csr_src[idx] : 0;
        int cnt = min(64, end - base);
        int j = 0;
        for (; j + 4 <= cnt; j += 4) {
            int s0 = __shfl(sj, j);
            int s1 = __shfl(sj, j + 1);
            int s2 = __shfl(sj, j + 2);
            int s3 = __shfl(sj, j + 3);
            uintT v0 = *reinterpret_cast<const uintT*>(h2 + (size_t)s0 * HF + lane * 2);
            uintT v1 = *reinterpret_cast<const uintT*>(h2 + (size_t)s1 * HF + lane * 2);
            uintT v2 = *reinterpret_cast<const uintT*>(h2 + (size_t)s2 * HF + lane * 2);
            uintT v3 = *reinterpret_cast<const uintT*>(h2 + (size_t)s3 * HF + lane * 2);
            a0 += bf2f(v0 & 0xffff); a1 += bf2f_hi(v0);
            a0 += bf2f(v1 & 0xffff); a1 += bf2f_hi(v1);
            a0 += bf2f(v2 & 0xffff); a1 += bf2f_hi(v2);
            a0 += bf2f(v3 & 0xffff); a1 += bf2f_hi(v3);
        }
        for (; j < cnt; ++j) {
            int s = __shfl(sj, j);
            uintT v = *reinterpret_cast<const uintT*>(h2 + (size_t)s * HF + lane * 2);
            a0 += bf2f(v & 0xffff); a1 += bf2f_hi(v);
        }
    }
    float dd = dis[node];
    *reinterpret_cast<uintT*>(agg + (size_t)node * HF + lane * 2) = pack2(a0 * dd, a1 * dd);
}

// ---------------- BN stats / coef ----------------

__global__ __launch_bounds__(256) void bn_stats_kernel(const ushortT* __restrict__ a,
                                                       float* __restrict__ stats, int n) {
    int lane = threadIdx.x & 63;
    int sub = threadIdx.x >> 6;
    float s0 = 0.f, s1 = 0.f, ss0 = 0.f, ss1 = 0.f;
    for (int r = blockIdx.x * 4 + sub; r < n; r += gridDim.x * 4) {
        uintT v = *reinterpret_cast<const uintT*>(a + (size_t)r * HF + lane * 2);
        float x0 = bf2f(v & 0xffff), x1 = bf2f_hi(v);
        s0 += x0; ss0 += x0 * x0;
        s1 += x1; ss1 += x1 * x1;
    }
    __shared__ float red[4][4][64];
    red[0][sub][lane] = s0; red[1][sub][lane] = s1;
    red[2][sub][lane] = ss0; red[3][sub][lane] = ss1;
    __syncthreads();
    if (sub == 0) {
        float S0 = red[0][0][lane] + red[0][1][lane] + red[0][2][lane] + red[0][3][lane];
        float S1 = red[1][0][lane] + red[1][1][lane] + red[1][2][lane] + red[1][3][lane];
        float T0 = red[2][0][lane] + red[2][1][lane] + red[2][2][lane] + red[2][3][lane];
        float T1 = red[3][0][lane] + red[3][1][lane] + red[3][2][lane] + red[3][3][lane];
        atomicAdd(&stats[lane * 2], S0);
        atomicAdd(&stats[lane * 2 + 1], S1);
        atomicAdd(&stats[HF + lane * 2], T0);
        atomicAdd(&stats[HF + lane * 2 + 1], T1);
    }
}

__global__ void bn_coef_kernel(const float* __restrict__ stats, const float* __restrict__ g,
                               const float* __restrict__ beta, float* __restrict__ coef,
                               float invn) {
    int j = threadIdx.x;
    if (j < HF) {
        float m = stats[j] * invn;
        float v = stats[HF + j] * invn - m * m;
        float sc = g[j] * rsqrtf(v + BN_EPS);
        coef[j] = sc;
        coef[HF + j] = beta[j] - m * sc;
    }
}

// ---------------- pooling (fused BN+ReLU of layer 2) ----------------

__global__ void starts_kernel(const int* __restrict__ batch, int* __restrict__ starts, int n) {
    int g = threadIdx.x;
    if (g > NG) return;
    int lo = 0, hi = n;
    while (lo < hi) {
        int mid = (lo + hi) >> 1;
        if (batch[mid] < g) lo = mid + 1; else hi = mid;
    }
    starts[g] = lo;
}

__global__ void pool_kernel(const ushortT* __restrict__ h, const float* __restrict__ coef,
                            const int* __restrict__ starts, float* __restrict__ pooled) {
    int g = blockIdx.x >> 4;
    int p = blockIdx.x & 15;
    int lane = threadIdx.x;
    float sc0 = coef[lane * 2],     sc1 = coef[lane * 2 + 1];
    float sh0 = coef[HF + lane * 2], sh1 = coef[HF + lane * 2 + 1];
    int s = starts[g], e = starts[g + 1];
    int len = e - s;
    int chunk = (len + 15) >> 4;
    int r0 = s + p * chunk;
    int r1 = min(e, r0 + chunk);
    float a0 = 0.f, a1 = 0.f;
    for (int r = r0; r < r1; ++r) {
        uintT v = *reinterpret_cast<const uintT*>(h + (size_t)r * HF + lane * 2);
        a0 += fmaxf(bf2f(v & 0xffff) * sc0 + sh0, 0.f);
        a1 += fmaxf(bf2f_hi(v) * sc1 + sh1, 0.f);
    }
    if (r1 > r0) {
        atomicAdd(&pooled[g * HF + lane * 2], a0);
        atomicAdd(&pooled[g * HF + lane * 2 + 1], a1);
    }
}

// ---------------- head ----------------

__global__ __launch_bounds__(1024) void head_kernel(const float* __restrict__ pooled,
                                                    const int* __restrict__ starts,
                                                    const float* __restrict__ Wl,
                                                    const float* __restrict__ bl,
                                                    const float* __restrict__ Wo,
                                                    const float* __restrict__ bo,
                                                    float* __restrict__ out) {
    __shared__ float P[NG][HF];
    __shared__ float T[NG][HF];
    int t = threadIdx.x;
    for (int i = t; i < NG * HF; i += 1024) {
        int g = i >> 7;
        float cnt = fmaxf((float)(starts[g + 1] - starts[g]), 1.0f);
        P[g][i & 127] = pooled[i] / cnt;
    }
    __syncthreads();
    for (int i = t; i < NG * HF; i += 1024) {
        int g = i >> 7, j = i & 127;
        float acc = bl[j];
        for (int k = 0; k < HF; ++k) acc += P[g][k] * Wl[k * HF + j];
        T[g][j] = fmaxf(acc, 0.f);
    }
    __syncthreads();
    int g = t >> 4, o = t & 15;
    float acc = bo[o];
    for (int k = 0; k < HF; ++k) acc += T[g][k] * Wo[k * OUTF + o];
    out[t] = acc;
}

// ---------------- launch ----------------

extern "C" void kernel_launch(void* const* d_in, const int* in_sizes, int n_in,
                              void* d_out, int out_size, void* d_ws, size_t ws_size,
                              hipStream_t stream) {
    const float* x     = (const float*)d_in[0];
    const int*   ei    = (const int*)d_in[1];
    const int*   batch = (const int*)d_in[2];
    const float* W0 = (const float*)d_in[3];
    const float* g0 = (const float*)d_in[5];
    const float* be0 = (const float*)d_in[6];
    const float* W1 = (const float*)d_in[7];
    const float* g1 = (const float*)d_in[9];
    const float* be1 = (const float*)d_in[10];
    const float* W2 = (const float*)d_in[11];
    const float* g2 = (const float*)d_in[13];
    const float* be2 = (const float*)d_in[14];
    const float* Wl = (const float*)d_in[15];
    const float* bl = (const float*)d_in[16];
    const float* Wo = (const float*)d_in[17];
    const float* bo = (const float*)d_in[18];

    const int n = in_sizes[0];
    const int E = in_sizes[1] / 2;
    const int* srcI = ei;
    const int* dstI = ei + E;
    const int PB = (n + NB - 1) / NB;       // 98 for n=100000; pack assumes PB<=256, n<2^18

    ushortT* bufA = (ushortT*)d_ws;                      // n*HF bf16
    ushortT* bufB = bufA + (size_t)n * HF;               // n*HF bf16
    float* dis    = (float*)(bufB + (size_t)n * HF);     // n
    float* xp     = dis + n;                             // n
    float* aggx   = xp + n;                              // n
    float* stats  = aggx + n;                            // 2*HF + 4 (16B pad)
    float* coef   = stats + 2 * HF + 4;                  // 2*HF (16B aligned)
    float* pooled = coef + 2 * HF;                       // NG*HF
    int* degi     = (int*)(pooled + NG * HF);            // n
    int* rowptr   = degi + n;                            // n+1
    int* bcur     = rowptr + n + 1;                      // NB
    int* csr_src  = bcur + NB;                           // E
    uintT* tmp    = (uintT*)(csr_src + E);               // E
    int* blocksums = (int*)(tmp + E);                    // 256
    int* starts   = blocksums + 256;                     // NG+1
    float* stats1 = stats + 2 * HF;                      // 2 scalars

    const int nbScan = (n + 1023) / 1024;
    const int nbChunk = (E + CHUNK - 1) / CHUNK;

    // ---- CSR build: degree -> rowptr -> hierarchical bucket scatter -> reorder ----
    hipMemsetAsync(degi, 0, (size_t)n * 4, stream);
    degi_kernel<<<(E + 255) / 256, 256, 0, stream>>>(dstI, degi, E);
    dis_xp_kernel<<<(n + 255) / 256, 256, 0, stream>>>(degi, x, dis, xp, n);
    scan_partial<<<nbScan, 256, 0, stream>>>(degi, blocksums, n);
    scan_sums<<<1, 64, 0, stream>>>(blocksums, nbScan);
    scan_final<<<nbScan, 256, 0, stream>>>(degi, blocksums, rowptr, n);
    binit_kernel<<<(NB + 255) / 256, 256, 0, stream>>>(rowptr, bcur, n, PB);
    hist_scatter_kernel<<<nbChunk, 256, 0, stream>>>(srcI, dstI, bcur, tmp, E, PB);
    bucket_reorder_kernel<<<NB, 256, 0, stream>>>(tmp, rowptr, csr_src, n, PB);

    // ---- layer 0 (rank-1) ----
    gather1_kernel<<<(n + 255) / 256, 256, 0, stream>>>(xp, rowptr, csr_src, dis, aggx, n);
    hipMemsetAsync(stats1, 0, 2 * 4, stream);
    stats1_kernel<<<256, 256, 0, stream>>>(aggx, stats1, n);
    coef0_kernel<<<1, 128, 0, stream>>>(stats1, W0, g0, be0, coef, 1.0f / n);
    h0_kernel<<<(n * 32 + 255) / 256, 256, 0, stream>>>(aggx, coef, bufA, n);

    // ---- layer 1 ----
    gemm_mfma_kernel<<<(n + 63) / 64, 256, 0, stream>>>(bufA, W1, coef, dis, bufB, n, 0);
    gather128_kernel<<<(n * 64 + 255) / 256, 256, 0, stream>>>(bufB, rowptr, csr_src, dis, bufA, n);
    hipMemsetAsync(stats, 0, 2 * HF * 4, stream);
    bn_stats_kernel<<<512, 256, 0, stream>>>(bufA, stats, n);
    bn_coef_kernel<<<1, 128, 0, stream>>>(stats, g1, be1, coef, 1.0f / n);

    // ---- layer 2 ----
    gemm_mfma_kernel<<<(n + 63) / 64, 256, 0, stream>>>(bufA, W2, coef, dis, bufB, n, 1);
    gather128_kernel<<<(n * 64 + 255) / 256, 256, 0, stream>>>(bufB, rowptr, csr_src, dis, bufA, n);
    hipMemsetAsync(stats, 0, 2 * HF * 4, stream);
    bn_stats_kernel<<<512, 256, 0, stream>>>(bufA, stats, n);
    bn_coef_kernel<<<1, 128, 0, stream>>>(stats, g2, be2, coef, 1.0f / n);

    // ---- pool (fused BN+ReLU) + head ----
    starts_kernel<<<1, 128, 0, stream>>>(batch, starts, n);
    hipMemsetAsync(pooled, 0, NG * HF * 4, stream);
    pool_kernel<<<NG * 16, 64, 0, stream>>>(bufA, coef, starts, pooled);
    head_kernel<<<1, 1024, 0, stream>>>(pooled, starts, Wl, bl, Wo, bo, (float*)d_out);
}

// Round 8
// 455.842 us; speedup vs baseline: 2.0462x; 1.2006x over previous
//
#include <hip/hip_runtime.h>

#define HF 128
#define OUTF 16
#define NG 64
#define PBSH 7             // bucket = dst >> 7 (PB = 128 nodes/bucket)
#define PBSZ 128
#define CHUNK 16384        // edges per histogram/scatter block
#define STAGE 4608         // reorder LDS stage entries (avg bucket ~2046)
#define BN_EPS 1e-5f

typedef unsigned short ushortT;
typedef unsigned int uintT;
typedef __attribute__((ext_vector_type(8))) short bf16x8;
typedef __attribute__((ext_vector_type(4))) float f32x4;

__device__ __forceinline__ float bf2f(uintT u) {
    union { uintT i; float f; } c; c.i = u << 16; return c.f;
}
__device__ __forceinline__ float bf2f_hi(uintT u) {
    union { uintT i; float f; } c; c.i = u & 0xffff0000u; return c.f;
}
__device__ __forceinline__ uintT f2bf(float f) {
    union { float f; uintT i; } c; c.f = f;
    uintT u = c.i;
    return (u + 0x7fffu + ((u >> 16) & 1u)) >> 16;
}
__device__ __forceinline__ uintT pack2(float a, float b) {
    return f2bf(a) | (f2bf(b) << 16);
}

// ---------------- CSR build, atomic-free (global) ----------------

// Pass A: per-block LDS histogram over buckets, coalesced private output.
__global__ __launch_bounds__(1024) void bhist_kernel(const int* __restrict__ dst,
                                                     int* __restrict__ bhistB,
                                                     int E, int nbkt) {
    __shared__ int h[1024];
    int t = threadIdx.x, blk = blockIdx.x;
    if (t < 1024) h[t] = 0;
    __syncthreads();
    int e0 = blk * CHUNK, e1 = min(E, e0 + CHUNK);
    for (int e = e0 + t; e < e1; e += 1024) atomicAdd(&h[dst[e] >> PBSH], 1);
    __syncthreads();
    if (t < nbkt) bhistB[blk * 1024 + t] = h[t];
}

// Per-bucket serial scan across blocks: lbase[blk][bkt], total[bkt].
__global__ __launch_bounds__(256) void bscan_blocks_kernel(const int* __restrict__ bhistB,
                                                           int* __restrict__ lbase,
                                                           int* __restrict__ total,
                                                           int nblk, int nbkt) {
    int bkt = blockIdx.x * 256 + threadIdx.x;
    if (bkt >= nbkt) return;
    int run = 0;
    for (int blk = 0; blk < nblk; ++blk) {
        int c = bhistB[blk * 1024 + bkt];
        lbase[blk * 1024 + bkt] = run;
        run += c;
    }
    total[bkt] = run;
}

// Exclusive scan over bucket totals -> bbase[0..nbkt] (bbase[nbkt] = E).
__global__ __launch_bounds__(1024) void bscan_base_kernel(const int* __restrict__ total,
                                                          int* __restrict__ bbase, int nbkt) {
    __shared__ int sc[1024];
    int t = threadIdx.x;
    int v = (t < nbkt) ? total[t] : 0;
    sc[t] = v;
    __syncthreads();
    for (int o = 1; o < 1024; o <<= 1) {
        int add = (t >= o) ? sc[t - o] : 0;
        __syncthreads();
        sc[t] += add;
        __syncthreads();
    }
    if (t < nbkt) {
        bbase[t] = sc[t] - v;
        if (t == nbkt - 1) bbase[nbkt] = sc[t];
    }
}

// Pass B: scatter edges into bucketed tmp via LDS cursors (no global atomics).
// tmp[pos] = (local_dst << 18) | src.
__global__ __launch_bounds__(1024) void bscatter_kernel(const int* __restrict__ src,
                                                        const int* __restrict__ dst,
                                                        const int* __restrict__ bbase,
                                                        const int* __restrict__ lbase,
                                                        uintT* __restrict__ tmp,
                                                        int E, int nbkt) {
    __shared__ int cur[1024];
    int t = threadIdx.x, blk = blockIdx.x;
    if (t < nbkt) cur[t] = bbase[t] + lbase[blk * 1024 + t];
    __syncthreads();
    int e0 = blk * CHUNK, e1 = min(E, e0 + CHUNK);
    for (int e = e0 + t; e < e1; e += 1024) {
        int d = dst[e];
        int bkt = d >> PBSH;
        int pos = atomicAdd(&cur[bkt], 1);
        tmp[pos] = ((uintT)(d & (PBSZ - 1)) << 18) | (uintT)src[e];
    }
}

// Per-bucket: local degrees (=> rowptr, dis, xp) + in-bucket reorder to csr_src.
__global__ __launch_bounds__(256) void breorder_kernel(const uintT* __restrict__ tmp,
                                                       const int* __restrict__ bbase,
                                                       const float* __restrict__ x,
                                                       int* __restrict__ rowptr,
                                                       int* __restrict__ csr_src,
                                                       float* __restrict__ dis,
                                                       float* __restrict__ xp,
                                                       int n, int nbkt) {
    __shared__ int lcnt[PBSZ];
    __shared__ int sc[PBSZ];
    __shared__ int lcur[PBSZ];
    __shared__ int stage[STAGE];
    int b = blockIdx.x, t = threadIdx.x;
    int n0 = b << PBSH;
    if (n0 >= n) return;
    int start = bbase[b], end = bbase[b + 1];
    int cnt = end - start;
    if (t < PBSZ) lcnt[t] = 0;
    __syncthreads();
    for (int i = t; i < cnt; i += 256) atomicAdd(&lcnt[tmp[start + i] >> 18], 1);
    __syncthreads();
    int v = (t < PBSZ) ? lcnt[t] : 0;
    if (t < PBSZ) sc[t] = v;
    __syncthreads();
    for (int o = 1; o < PBSZ; o <<= 1) {
        int add = (t < PBSZ && t >= o) ? sc[t - o] : 0;
        __syncthreads();
        if (t < PBSZ) sc[t] += add;
        __syncthreads();
    }
    if (t < PBSZ) {
        int pre = sc[t] - v;
        lcur[t] = pre;
        int node = n0 + t;
        if (node < n) {
            rowptr[node] = start + pre;
            float d = rsqrtf((float)v + 1.0f);      // +1 = self loop
            dis[node] = d;
            xp[node] = d * x[node];
        }
    }
    if (b == nbkt - 1 && t == 0) rowptr[n] = end;
    __syncthreads();
    if (cnt <= STAGE) {
        for (int i = t; i < cnt; i += 256) {
            uintT p = tmp[start + i];
            int pos = atomicAdd(&lcur[p >> 18], 1);
            stage[pos] = (int)(p & 0x3ffffu);
        }
        __syncthreads();
        for (int i = t; i < cnt; i += 256) csr_src[start + i] = stage[i];
    } else {
        for (int i = t; i < cnt; i += 256) {
            uintT p = tmp[start + i];
            int pos = atomicAdd(&lcur[p >> 18], 1);
            csr_src[start + pos] = (int)(p & 0x3ffffu);
        }
    }
}

// ---------------- layer 0: scalar gather (xp = dis*x) ----------------

__global__ void gather1_kernel(const float* __restrict__ xp, const int* __restrict__ rowptr,
                               const int* __restrict__ csr_src, const float* __restrict__ dis,
                               float* __restrict__ aggx, int n) {
    int i = blockIdx.x * blockDim.x + threadIdx.x;
    if (i >= n) return;
    float acc = xp[i];                // self loop
    int e = rowptr[i + 1];
    for (int j = rowptr[i]; j < e; ++j) acc += xp[csr_src[j]];
    aggx[i] = acc * dis[i];
}

__global__ void stats1_kernel(const float* __restrict__ aggx, float* __restrict__ stats1, int n) {
    float s = 0.f, ss = 0.f;
    for (int i = blockIdx.x * blockDim.x + threadIdx.x; i < n; i += gridDim.x * blockDim.x) {
        float v = aggx[i]; s += v; ss += v * v;
    }
    for (int o = 32; o > 0; o >>= 1) { s += __shfl_down(s, o); ss += __shfl_down(ss, o); }
    if ((threadIdx.x & 63) == 0) { atomicAdd(&stats1[0], s); atomicAdd(&stats1[1], ss); }
}

__global__ void coef0_kernel(const float* __restrict__ stats1, const float* __restrict__ W0,
                             const float* __restrict__ g, const float* __restrict__ beta,
                             float* __restrict__ coef, float invn) {
    int j = threadIdx.x;
    if (j < HF) {
        float m = stats1[0] * invn;
        float var = stats1[1] * invn - m * m;
        float w = W0[j];
        float sc = g[j] * w * rsqrtf(var * w * w + BN_EPS);
        coef[j] = sc;
        coef[HF + j] = beta[j] - m * sc;
    }
}

__global__ void h0_kernel(const float* __restrict__ aggx, const float* __restrict__ coef,
                          ushortT* __restrict__ h0, int n) {
    int idx = blockIdx.x * blockDim.x + threadIdx.x;
    if (idx >= n * (HF / 4)) return;
    int i = idx >> 5, jc = idx & 31;
    float a = aggx[i];
    float4 sc = reinterpret_cast<const float4*>(coef)[jc];
    float4 sh = reinterpret_cast<const float4*>(coef + HF)[jc];
    float o0 = fmaxf(a * sc.x + sh.x, 0.f);
    float o1 = fmaxf(a * sc.y + sh.y, 0.f);
    float o2 = fmaxf(a * sc.z + sh.z, 0.f);
    float o3 = fmaxf(a * sc.w + sh.w, 0.f);
    uint2 o; o.x = pack2(o0, o1); o.y = pack2(o2, o3);
    reinterpret_cast<uint2*>(h0)[idx] = o;
}

// ---------------- MFMA GEMM: C[n,128] = dis[row] * (act(A)[n,128] @ W[128,128]) ----------------

__global__ __launch_bounds__(256) void gemm_mfma_kernel(const ushortT* __restrict__ A,
                                                        const float* __restrict__ W,
                                                        const float* __restrict__ coef,
                                                        const float* __restrict__ dis,
                                                        ushortT* __restrict__ C, int n,
                                                        int applyCoef) {
    __shared__ ushortT Wt[128 * 128];   // 32 KB, Wt[col][k] bf16, swizzled
    int t = threadIdx.x;
    int wave = t >> 6, lane = t & 63;
    int l4 = lane >> 4;
    int lm = lane & 15;

    for (int i = t; i < 128 * 128; i += 256) {
        int k = i >> 7, j = i & 127;
        int byteoff = (j << 8) + ((k << 1) ^ ((j & 7) << 4));
        *(ushortT*)((char*)Wt + byteoff) = (ushortT)f2bf(W[i]);
    }
    __syncthreads();

    int rowBase = blockIdx.x * 64 + wave * 16;
    int ar = rowBase + lm;
    int arc = min(ar, n - 1);

    bf16x8 af[4];
    #pragma unroll
    for (int kb = 0; kb < 4; ++kb) {
        int k0 = kb * 32 + l4 * 8;
        bf16x8 v = *reinterpret_cast<const bf16x8*>(A + (size_t)arc * HF + k0);
        if (applyCoef) {
            float4 sc0 = *reinterpret_cast<const float4*>(coef + k0);
            float4 sc1 = *reinterpret_cast<const float4*>(coef + k0 + 4);
            float4 sh0 = *reinterpret_cast<const float4*>(coef + HF + k0);
            float4 sh1 = *reinterpret_cast<const float4*>(coef + HF + k0 + 4);
            float scv[8] = {sc0.x, sc0.y, sc0.z, sc0.w, sc1.x, sc1.y, sc1.z, sc1.w};
            float shv[8] = {sh0.x, sh0.y, sh0.z, sh0.w, sh1.x, sh1.y, sh1.z, sh1.w};
            bf16x8 o;
            #pragma unroll
            for (int j = 0; j < 8; ++j) {
                float f = bf2f((uintT)(ushortT)v[j]);
                f = fmaxf(f * scv[j] + shv[j], 0.f);
                o[j] = (short)f2bf(f);
            }
            v = o;
        }
        af[kb] = v;
    }

    f32x4 acc[8];
    #pragma unroll
    for (int ct = 0; ct < 8; ++ct) acc[ct] = (f32x4){0.f, 0.f, 0.f, 0.f};

    #pragma unroll
    for (int ct = 0; ct < 8; ++ct) {
        int col = ct * 16 + lm;
        int rowbyte = col << 8;
        int swz = (col & 7) << 4;
        #pragma unroll
        for (int kb = 0; kb < 4; ++kb) {
            int off = ((kb * 64 + l4 * 16) ^ swz);
            bf16x8 bf = *reinterpret_cast<const bf16x8*>((const char*)Wt + rowbyte + off);
            acc[ct] = __builtin_amdgcn_mfma_f32_16x16x32_bf16(af[kb], bf, acc[ct], 0, 0, 0);
        }
    }

    int rbase = rowBase + l4 * 4;
    float4 d4;
    if (rbase <= n - 4) {
        d4 = *reinterpret_cast<const float4*>(dis + rbase);
    } else {
        float tmp4[4];
        #pragma unroll
        for (int r = 0; r < 4; ++r) tmp4[r] = (rbase + r < n) ? dis[rbase + r] : 0.f;
        d4 = make_float4(tmp4[0], tmp4[1], tmp4[2], tmp4[3]);
    }
    const float* dd = (const float*)&d4;
    #pragma unroll
    for (int ct = 0; ct < 8; ++ct) {
        #pragma unroll
        for (int r = 0; r < 4; ++r) {
            float v = acc[ct][r] * dd[r];
            float o = __shfl_xor(v, 1);
            int row = rbase + r;
            if ((lane & 1) == 0 && row < n) {
                *(uintT*)(C + (size_t)row * HF + ct * 16 + lm) = pack2(v, o);
            }
        }
    }
}

// ---------------- CSR gather: agg[d] = dis[d]*(sum src rows + own row) ----------------

__global__ __launch_bounds__(256) void gather128_kernel(const ushortT* __restrict__ h2,
                                                        const int* __restrict__ rowptr,
                                                        const int* __restrict__ csr_src,
                                                        const float* __restrict__ dis,
                                                        ushortT* __restrict__ agg, int n) {
    int node = (blockIdx.x * 256 + threadIdx.x) >> 6;
    int lane = threadIdx.x & 63;
    if (node >= n) return;
    int beg = rowptr[node], end = rowptr[node + 1];
    uintT vs = *reinterpret_cast<const uintT*>(h2 + (size_t)node * HF + lane * 2);
    float a0 = bf2f(vs & 0xffff), a1 = bf2f_hi(vs);
    for (int base = beg; base < end; base += 64) {
        int idx = base + lane;
        int sj = (idx < end) ? csr_src[idx] : 0;
        int cnt = min(64, end - base);
        int j = 0;
        for (; j + 4 <= cnt; j += 4) {
            int s0 = __shfl(sj, j);
            int s1 = __shfl(sj, j + 1);
            int s2 = __shfl(sj, j + 2);
            int s3 = __shfl(sj, j + 3);
            uintT v0 = *reinterpret_cast<const uintT*>(h2 + (size_t)s0 * HF + lane * 2);
            uintT v1 = *reinterpret_cast<const uintT*>(h2 + (size_t)s1 * HF + lane * 2);
            uintT v2 = *reinterpret_cast<const uintT*>(h2 + (size_t)s2 * HF + lane * 2);
            uintT v3 = *reinterpret_cast<const uintT*>(h2 + (size_t)s3 * HF + lane * 2);
            a0 += bf2f(v0 & 0xffff); a1 += bf2f_hi(v0);
            a0 += bf2f(v1 & 0xffff); a1 += bf2f_hi(v1);
            a0 += bf2f(v2 & 0xffff); a1 += bf2f_hi(v2);
            a0 += bf2f(v3 & 0xffff); a1 += bf2f_hi(v3);
        }
        for (; j < cnt; ++j) {
            int s = __shfl(sj, j);
            uintT v = *reinterpret_cast<const uintT*>(h2 + (size_t)s * HF + lane * 2);
            a0 += bf2f(v & 0xffff); a1 += bf2f_hi(v);
        }
    }
    float dd = dis[node];
    *reinterpret_cast<uintT*>(agg + (size_t)node * HF + lane * 2) = pack2(a0 * dd, a1 * dd);
}

// ---------------- BN stats / coef ----------------

__global__ __launch_bounds__(256) void bn_stats_kernel(const ushortT* __restrict__ a,
                                                       float* __restrict__ stats, int n) {
    int lane = threadIdx.x & 63;
    int sub = threadIdx.x >> 6;
    float s0 = 0.f, s1 = 0.f, ss0 = 0.f, ss1 = 0.f;
    for (int r = blockIdx.x * 4 + sub; r < n; r += gridDim.x * 4) {
        uintT v = *reinterpret_cast<const uintT*>(a + (size_t)r * HF + lane * 2);
        float x0 = bf2f(v & 0xffff), x1 = bf2f_hi(v);
        s0 += x0; ss0 += x0 * x0;
        s1 += x1; ss1 += x1 * x1;
    }
    __shared__ float red[4][4][64];
    red[0][sub][lane] = s0; red[1][sub][lane] = s1;
    red[2][sub][lane] = ss0; red[3][sub][lane] = ss1;
    __syncthreads();
    if (sub == 0) {
        float S0 = red[0][0][lane] + red[0][1][lane] + red[0][2][lane] + red[0][3][lane];
        float S1 = red[1][0][lane] + red[1][1][lane] + red[1][2][lane] + red[1][3][lane];
        float T0 = red[2][0][lane] + red[2][1][lane] + red[2][2][lane] + red[2][3][lane];
        float T1 = red[3][0][lane] + red[3][1][lane] + red[3][2][lane] + red[3][3][lane];
        atomicAdd(&stats[lane * 2], S0);
        atomicAdd(&stats[lane * 2 + 1], S1);
        atomicAdd(&stats[HF + lane * 2], T0);
        atomicAdd(&stats[HF + lane * 2 + 1], T1);
    }
}

__global__ void bn_coef_kernel(const float* __restrict__ stats, const float* __restrict__ g,
                               const float* __restrict__ beta, float* __restrict__ coef,
                               float invn) {
    int j = threadIdx.x;
    if (j < HF) {
        float m = stats[j] * invn;
        float v = stats[HF + j] * invn - m * m;
        float sc = g[j] * rsqrtf(v + BN_EPS);
        coef[j] = sc;
        coef[HF + j] = beta[j] - m * sc;
    }
}

// ---------------- pooling (fused BN+ReLU of layer 2) ----------------

__global__ void starts_kernel(const int* __restrict__ batch, int* __restrict__ starts, int n) {
    int g = threadIdx.x;
    if (g > NG) return;
    int lo = 0, hi = n;
    while (lo < hi) {
        int mid = (lo + hi) >> 1;
        if (batch[mid] < g) lo = mid + 1; else hi = mid;
    }
    starts[g] = lo;
}

__global__ void pool_kernel(const ushortT* __restrict__ h, const float* __restrict__ coef,
                            const int* __restrict__ starts, float* __restrict__ pooled) {
    int g = blockIdx.x >> 4;
    int p = blockIdx.x & 15;
    int lane = threadIdx.x;
    float sc0 = coef[lane * 2],     sc1 = coef[lane * 2 + 1];
    float sh0 = coef[HF + lane * 2], sh1 = coef[HF + lane * 2 + 1];
    int s = starts[g], e = starts[g + 1];
    int len = e - s;
    int chunk = (len + 15) >> 4;
    int r0 = s + p * chunk;
    int r1 = min(e, r0 + chunk);
    float a0 = 0.f, a1 = 0.f;
    for (int r = r0; r < r1; ++r) {
        uintT v = *reinterpret_cast<const uintT*>(h + (size_t)r * HF + lane * 2);
        a0 += fmaxf(bf2f(v & 0xffff) * sc0 + sh0, 0.f);
        a1 += fmaxf(bf2f_hi(v) * sc1 + sh1, 0.f);
    }
    if (r1 > r0) {
        atomicAdd(&pooled[g * HF + lane * 2], a0);
        atomicAdd(&pooled[g * HF + lane * 2 + 1], a1);
    }
}

// ---------------- head ----------------

__global__ __launch_bounds__(1024) void head_kernel(const float* __restrict__ pooled,
                                                    const int* __restrict__ starts,
                                                    const float* __restrict__ Wl,
                                                    const float* __restrict__ bl,
                                                    const float* __restrict__ Wo,
                                                    const float* __restrict__ bo,
                                                    float* __restrict__ out) {
    __shared__ float P[NG][HF];
    __shared__ float T[NG][HF];
    int t = threadIdx.x;
    for (int i = t; i < NG * HF; i += 1024) {
        int g = i >> 7;
        float cnt = fmaxf((float)(starts[g + 1] - starts[g]), 1.0f);
        P[g][i & 127] = pooled[i] / cnt;
    }
    __syncthreads();
    for (int i = t; i < NG * HF; i += 1024) {
        int g = i >> 7, j = i & 127;
        float acc = bl[j];
        for (int k = 0; k < HF; ++k) acc += P[g][k] * Wl[k * HF + j];
        T[g][j] = fmaxf(acc, 0.f);
    }
    __syncthreads();
    int g = t >> 4, o = t & 15;
    float acc = bo[o];
    for (int k = 0; k < HF; ++k) acc += T[g][k] * Wo[k * OUTF + o];
    out[t] = acc;
}

// ---------------- launch ----------------

extern "C" void kernel_launch(void* const* d_in, const int* in_sizes, int n_in,
                              void* d_out, int out_size, void* d_ws, size_t ws_size,
                              hipStream_t stream) {
    const float* x     = (const float*)d_in[0];
    const int*   ei    = (const int*)d_in[1];
    const int*   batch = (const int*)d_in[2];
    const float* W0 = (const float*)d_in[3];
    const float* g0 = (const float*)d_in[5];
    const float* be0 = (const float*)d_in[6];
    const float* W1 = (const float*)d_in[7];
    const float* g1 = (const float*)d_in[9];
    const float* be1 = (const float*)d_in[10];
    const float* W2 = (const float*)d_in[11];
    const float* g2 = (const float*)d_in[13];
    const float* be2 = (const float*)d_in[14];
    const float* Wl = (const float*)d_in[15];
    const float* bl = (const float*)d_in[16];
    const float* Wo = (const float*)d_in[17];
    const float* bo = (const float*)d_in[18];

    const int n = in_sizes[0];
    const int E = in_sizes[1] / 2;
    const int* srcI = ei;
    const int* dstI = ei + E;
    const int nbkt = (n + PBSZ - 1) >> PBSH;            // 782 for n=100000 (<=1024)
    const int nblk = (E + CHUNK - 1) / CHUNK;           // 98

    ushortT* bufA = (ushortT*)d_ws;                      // n*HF bf16
    ushortT* bufB = bufA + (size_t)n * HF;               // n*HF bf16
    float* dis    = (float*)(bufB + (size_t)n * HF);     // n
    float* xp     = dis + n;                             // n
    float* aggx   = xp + n;                              // n
    float* stats  = aggx + n;                            // 2*HF + 4 (16B pad)
    float* coef   = stats + 2 * HF + 4;                  // 2*HF (16B aligned)
    float* pooled = coef + 2 * HF;                       // NG*HF
    int* rowptr   = (int*)(pooled + NG * HF);            // n+1
    int* csr_src  = rowptr + n + 1;                      // E
    uintT* tmp    = (uintT*)(csr_src + E);               // E
    int* bhistB   = (int*)(tmp + E);                     // nblk*1024
    int* lbase    = bhistB + (size_t)nblk * 1024;        // nblk*1024
    int* total    = lbase + (size_t)nblk * 1024;         // 1024
    int* bbase    = total + 1024;                        // nbkt+1
    int* starts   = bbase + 1025;                        // NG+1
    float* stats1 = stats + 2 * HF;                      // 2 scalars

    // ---- CSR build (atomic-free): bhist -> scans -> bscatter -> breorder ----
    bhist_kernel<<<nblk, 1024, 0, stream>>>(dstI, bhistB, E, nbkt);
    bscan_blocks_kernel<<<(nbkt + 255) / 256, 256, 0, stream>>>(bhistB, lbase, total, nblk, nbkt);
    bscan_base_kernel<<<1, 1024, 0, stream>>>(total, bbase, nbkt);
    bscatter_kernel<<<nblk, 1024, 0, stream>>>(srcI, dstI, bbase, lbase, tmp, E, nbkt);
    breorder_kernel<<<nbkt, 256, 0, stream>>>(tmp, bbase, x, rowptr, csr_src, dis, xp, n, nbkt);

    // ---- layer 0 (rank-1) ----
    gather1_kernel<<<(n + 255) / 256, 256, 0, stream>>>(xp, rowptr, csr_src, dis, aggx, n);
    hipMemsetAsync(stats1, 0, 2 * 4, stream);
    stats1_kernel<<<256, 256, 0, stream>>>(aggx, stats1, n);
    coef0_kernel<<<1, 128, 0, stream>>>(stats1, W0, g0, be0, coef, 1.0f / n);
    h0_kernel<<<(n * 32 + 255) / 256, 256, 0, stream>>>(aggx, coef, bufA, n);

    // ---- layer 1 ----
    gemm_mfma_kernel<<<(n + 63) / 64, 256, 0, stream>>>(bufA, W1, coef, dis, bufB, n, 0);
    gather128_kernel<<<(n * 64 + 255) / 256, 256, 0, stream>>>(bufB, rowptr, csr_src, dis, bufA, n);
    hipMemsetAsync(stats, 0, 2 * HF * 4, stream);
    bn_stats_kernel<<<512, 256, 0, stream>>>(bufA, stats, n);
    bn_coef_kernel<<<1, 128, 0, stream>>>(stats, g1, be1, coef, 1.0f / n);

    // ---- layer 2 ----
    gemm_mfma_kernel<<<(n + 63) / 64, 256, 0, stream>>>(bufA, W2, coef, dis, bufB, n, 1);
    gather128_kernel<<<(n * 64 + 255) / 256, 256, 0, stream>>>(bufB, rowptr, csr_src, dis, bufA, n);
    hipMemsetAsync(stats, 0, 2 * HF * 4, stream);
    bn_stats_kernel<<<512, 256, 0, stream>>>(bufA, stats, n);
    bn_coef_kernel<<<1, 128, 0, stream>>>(stats, g2, be2, coef, 1.0f / n);

    // ---- pool (fused BN+ReLU) + head ----
    starts_kernel<<<1, 128, 0, stream>>>(batch, starts, n);
    hipMemsetAsync(pooled, 0, NG * HF * 4, stream);
    pool_kernel<<<NG * 16, 64, 0, stream>>>(bufA, coef, starts, pooled);
    head_kernel<<<1, 1024, 0, stream>>>(pooled, starts, Wl, bl, Wo, bo, (float*)d_out);
}